// Round 1
// baseline (417.844 us; speedup 1.0000x reference)
//
#include <hip/hip_runtime.h>
#include <cmath>

#define PITCH 65
#define TWO_PI 6.283185307179586476925f

__device__ __forceinline__ float sigm(float v) { return 1.0f / (1.0f + expf(-v)); }

__device__ __forceinline__ float2 cmulf(float2 a, float2 b) {
    return make_float2(a.x * b.x - a.y * b.y, a.x * b.y + a.y * b.x);
}

__device__ __forceinline__ void dft4_fwd(float2& a0, float2& a1, float2& a2, float2& a3) {
    float t0r = a0.x + a2.x, t0i = a0.y + a2.y;
    float t1r = a0.x - a2.x, t1i = a0.y - a2.y;
    float t2r = a1.x + a3.x, t2i = a1.y + a3.y;
    float t3r = a1.x - a3.x, t3i = a1.y - a3.y;
    a0 = make_float2(t0r + t2r, t0i + t2i);
    a2 = make_float2(t0r - t2r, t0i - t2i);
    a1 = make_float2(t1r + t3i, t1i - t3r);   // (a0-a2) - i(a1-a3)
    a3 = make_float2(t1r - t3i, t1i + t3r);   // (a0-a2) + i(a1-a3)
}

__device__ __forceinline__ void dft4_inv(float2& a0, float2& a1, float2& a2, float2& a3) {
    float t0r = a0.x + a2.x, t0i = a0.y + a2.y;
    float t1r = a0.x - a2.x, t1i = a0.y - a2.y;
    float t2r = a1.x + a3.x, t2i = a1.y + a3.y;
    float t3r = a1.x - a3.x, t3i = a1.y - a3.y;
    a0 = make_float2(t0r + t2r, t0i + t2i);
    a2 = make_float2(t0r - t2r, t0i - t2i);
    a1 = make_float2(t1r - t3i, t1i + t3r);   // (b0-b2) + i(b1-b3)
    a3 = make_float2(t1r + t3i, t1i - t3r);   // (b0-b2) - i(b1-b3)
}

// In-LDS 64-point radix-4 FFT pass over 64 lines (rows or cols).
// Forward: DIF, natural in -> digit-reversed out. Inverse: exact stage-by-stage
// inverse (digit-reversed in -> natural out, unnormalized; total 2D scale 4096).
template<bool INV, bool COL>
__device__ void fft_pass(float2* a, const float2* tw, int tid, int lineLimit) {
#pragma unroll
    for (int si = 0; si < 3; ++si) {
        const int m = INV ? (4 << (2 * si)) : (64 >> (2 * si));
        const int q = m >> 2;
        __syncthreads();
#pragma unroll
        for (int k = 0; k < 4; ++k) {
            int beta = tid + 256 * k;
            int line = beta >> 4;
            int t = beta & 15;
            if (line < lineLimit) {
                int blk = t / q;          // q in {16,4,1}: folds to shifts
                int j = t - blk * q;
                int base = blk * m + j;
                int p0 = base, p1 = base + q, p2 = base + 2 * q, p3 = base + 3 * q;
                int e1 = j * (64 / m);
                int a0i = COL ? p0 * PITCH + line : line * PITCH + p0;
                int a1i = COL ? p1 * PITCH + line : line * PITCH + p1;
                int a2i = COL ? p2 * PITCH + line : line * PITCH + p2;
                int a3i = COL ? p3 * PITCH + line : line * PITCH + p3;
                float2 a0 = a[a0i], a1 = a[a1i], a2 = a[a2i], a3 = a[a3i];
                if (INV) {
                    float2 w1 = tw[e1], w2 = tw[2 * e1], w3 = tw[3 * e1];
                    w1.y = -w1.y; w2.y = -w2.y; w3.y = -w3.y;
                    a1 = cmulf(a1, w1); a2 = cmulf(a2, w2); a3 = cmulf(a3, w3);
                    dft4_inv(a0, a1, a2, a3);
                } else {
                    dft4_fwd(a0, a1, a2, a3);
                    a1 = cmulf(a1, tw[e1]);
                    a2 = cmulf(a2, tw[2 * e1]);
                    a3 = cmulf(a3, tw[3 * e1]);
                }
                a[a0i] = a0; a[a1i] = a1; a[a2i] = a2; a[a3i] = a3;
            }
        }
    }
    __syncthreads();
}

// ---------------- P1: 2-D SSM impulse response --------------------------------
// thread = (channel c in [0,3072), state n in [0,16)); 16-lane reduce over n.
__global__ __launch_bounds__(256, 1) void ssm_kernel(
        const float* __restrict__ Aang, const float* __restrict__ Arad,
        const float* __restrict__ B1p, const float* __restrict__ B2p,
        const float* __restrict__ C1p, const float* __restrict__ C2p,
        float* __restrict__ k4) {
    int gid = blockIdx.x * 256 + threadIdx.x;   // == c*16 + n
    int c = gid >> 4, n = gid & 15;

    float ar[4], ai[4];
#pragma unroll
    for (int t = 0; t < 4; ++t) {
        float ang = sigm(Aang[t * 49152 + gid]) * TWO_PI;
        float rad = sigm(Arad[t * 49152 + gid]);
        float s, co;
        sincosf(ang, &s, &co);
        ar[t] = rad * co; ai[t] = rad * s;
    }
    const float2* B1v = (const float2*)B1p;
    const float2* B2v = (const float2*)B2p;
    const float2* C1v = (const float2*)C1p;
    const float2* C2v = (const float2*)C2p;
    float2 b1 = B1v[gid], b2 = B2v[gid], c1 = C1v[gid], c2 = C2v[gid];
    float b1r = sigm(b1.x), b1i = sigm(b1.y);
    float b2r = sigm(b2.x), b2i = sigm(b2.y);
    float c1r = c1.x, c1i = c1.y, c2r = c2.x, c2i = c2.y;

    float xhr[32], xhi[32], xvr[32], xvi[32];
#pragma unroll
    for (int j = 0; j < 32; ++j) { xhr[j] = 0.f; xhi[j] = 0.f; xvr[j] = 0.f; xvi[j] = 0.f; }

    float* kout = k4 + c * 1024;
    for (int i = 0; i < 32; ++i) {
        // xv[i,j] = A3*xh[i-1,j] + A4*xv[i-1,j]   (+ B2 at (0,0))
#pragma unroll
        for (int j = 0; j < 32; ++j) {
            float nr = ar[2] * xhr[j] - ai[2] * xhi[j] + ar[3] * xvr[j] - ai[3] * xvi[j];
            float ni = ar[2] * xhi[j] + ai[2] * xhr[j] + ar[3] * xvi[j] + ai[3] * xvr[j];
            xvr[j] = nr; xvi[j] = ni;
        }
        if (i == 0) { xvr[0] += b2r; xvi[0] += b2i; }
        // xh[i,0] = B1 if i==0 else 0 ; xh[i,j] = A1*xh[i,j-1] + A2*xv[i,j-1]
        float hr = (i == 0) ? b1r : 0.f, hi = (i == 0) ? b1i : 0.f;
        xhr[0] = hr; xhi[0] = hi;
#pragma unroll
        for (int j = 1; j < 32; ++j) {
            float nr = ar[0] * hr - ai[0] * hi + ar[1] * xvr[j - 1] - ai[1] * xvi[j - 1];
            float ni = ar[0] * hi + ai[0] * hr + ar[1] * xvi[j - 1] + ai[1] * xvr[j - 1];
            hr = nr; hi = ni; xhr[j] = hr; xhi[j] = hi;
        }
        // k[i,j,c] = SCALE * sum_n Re(C1*xh + C2*xv), with edge factors
#pragma unroll
        for (int j = 0; j < 32; ++j) {
            float val = c1r * xhr[j] - c1i * xhi[j] + c2r * xvr[j] - c2i * xvi[j];
            val += __shfl_xor(val, 8, 16);
            val += __shfl_xor(val, 4, 16);
            val += __shfl_xor(val, 2, 16);
            val += __shfl_xor(val, 1, 16);
            if (n == 0) {
                float f = 1.f;
                if (i == 0 && j == 0) f = 1.f;
                else if (i == 0 || j == 0) f = 2.f;
                kout[i * 32 + j] = 0.25f * f * val;
            }
        }
    }
}

// ---------------- P2: combined-direction kernel -> spectrum -------------------
__global__ __launch_bounds__(256) void build_gf(const float* __restrict__ k4,
                                                float2* __restrict__ Gf) {
    __shared__ float2 a[64 * PITCH];
    __shared__ float2 tw[64];
    int d = blockIdx.x, tid = threadIdx.x;
    for (int e = tid; e < 64 * PITCH; e += 256) a[e] = make_float2(0.f, 0.f);
    if (tid < 64) {
        float s, co;
        sincosf(-TWO_PI * (float)tid / 64.0f, &s, &co);
        tw[tid] = make_float2(co, s);
    }
    __syncthreads();
    // H[t] = G[-t mod 64]; out[i,j] = sum_m x[m] H[(i-m) mod 64]
#pragma unroll
    for (int k = 0; k < 4; ++k) {
        int cell = tid + 256 * k;       // p*32+q
        int p = cell >> 5, q = cell & 31;
        float k0 = k4[(0 * 768 + d) * 1024 + cell];
        float k1 = k4[(1 * 768 + d) * 1024 + cell];
        float k2 = k4[(2 * 768 + d) * 1024 + cell];
        float k3 = k4[(3 * 768 + d) * 1024 + cell];
        int pn = (64 - p) & 63, qn = (64 - q) & 63;
        a[p  * PITCH + q ].x += k0;
        a[pn * PITCH + q ].x += k1;
        a[p  * PITCH + qn].x += k2;
        a[pn * PITCH + qn].x += k3;
    }
    fft_pass<false, false>(a, tw, tid, 64);   // rows
    fft_pass<false, true >(a, tw, tid, 64);   // cols
    for (int e = tid; e < 4096; e += 256) {
        int u = e >> 6, v = e & 63;
        Gf[d * 4096 + e] = a[u * PITCH + v];
    }
}

// ---------------- P3: FFT conv, two batch images packed re/im -----------------
__global__ __launch_bounds__(256) void conv_fft(
        const float* __restrict__ x, const float2* __restrict__ Gf,
        const float* __restrict__ omega, float* __restrict__ out,
        int directOut, float* __restrict__ outT) {
    __shared__ float2 a[64 * PITCH];
    __shared__ float2 xo[1024];
    __shared__ float2 tw[64];
    int bid = blockIdx.x;          // d*8 + bpair
    int d = bid >> 3, b = (bid & 7) * 2;
    int tid = threadIdx.x;

    for (int e = tid; e < 64 * PITCH; e += 256) a[e] = make_float2(0.f, 0.f);
    if (tid < 64) {
        float s, co;
        sincosf(-TWO_PI * (float)tid / 64.0f, &s, &co);
        tw[tid] = make_float2(co, s);
    }
    __syncthreads();
    for (int s = tid; s < 1024; s += 256) {
        float xa = x[s * 12288 + b * 768 + d];
        float xb = x[s * 12288 + (b + 1) * 768 + d];
        xo[s] = make_float2(xa, xb);
        a[(s >> 5) * PITCH + (s & 31)] = make_float2(xa, xb);
    }
    fft_pass<false, false>(a, tw, tid, 32);   // fwd rows (rows 32..63 are zero)
    fft_pass<false, true >(a, tw, tid, 64);   // fwd cols
    for (int e = tid; e < 4096; e += 256) {   // pointwise (digit-reversed aligned)
        int u = e >> 6, v = e & 63;
        a[u * PITCH + v] = cmulf(a[u * PITCH + v], Gf[d * 4096 + e]);
    }
    fft_pass<true, true >(a, tw, tid, 64);    // inv cols
    fft_pass<true, false>(a, tw, tid, 32);    // inv rows (only rows 0..31 needed)

    float w = omega[d];
    const float inv = 1.0f / 4096.0f;
    for (int s = tid; s < 1024; s += 256) {
        float2 cc = a[(s >> 5) * PITCH + (s & 31)];
        float2 xv = xo[s];
        float ya = cc.x * inv + xv.x * w;
        float yb = cc.y * inv + xv.y * w;
        float oa = ya / (1.0f + expf(-ya));
        float ob = yb / (1.0f + expf(-yb));
        if (directOut) {
            out[s * 12288 + b * 768 + d] = oa;
            out[s * 12288 + (b + 1) * 768 + d] = ob;
        } else {
            outT[(b * 768 + d) * 1024 + s] = oa;
            outT[((b + 1) * 768 + d) * 1024 + s] = ob;
        }
    }
}

// ---------------- P4: (B*D, S) -> (S, B*D) transpose --------------------------
__global__ __launch_bounds__(256) void transpose_out(const float* __restrict__ outT,
                                                     float* __restrict__ out) {
    __shared__ float t[32][33];
    int bR = blockIdx.x % 384, bS = blockIdx.x / 384;
    int r0 = bR * 32, s0 = bS * 32;
    int tx = threadIdx.x & 31, ty = threadIdx.x >> 5;
#pragma unroll
    for (int k = 0; k < 4; ++k) {
        int r = ty + 8 * k;
        t[r][tx] = outT[(r0 + r) * 1024 + s0 + tx];
    }
    __syncthreads();
#pragma unroll
    for (int k = 0; k < 4; ++k) {
        int r = ty + 8 * k;
        out[(s0 + r) * 12288 + r0 + tx] = t[tx][r];
    }
}

extern "C" void kernel_launch(void* const* d_in, const int* in_sizes, int n_in,
                              void* d_out, int out_size, void* d_ws, size_t ws_size,
                              hipStream_t stream) {
    const float* x     = (const float*)d_in[0];
    const float* Aang  = (const float*)d_in[1];
    const float* Arad  = (const float*)d_in[2];
    const float* B1p   = (const float*)d_in[3];
    const float* B2p   = (const float*)d_in[4];
    const float* C1p   = (const float*)d_in[5];
    const float* C2p   = (const float*)d_in[6];
    const float* omega = (const float*)d_in[7];
    float* out = (float*)d_out;
    char* ws = (char*)d_ws;

    float*  k4   = (float*)ws;                              // 12,582,912 B
    float2* Gf   = (float2*)(ws + 12582912);                // 25,165,824 B
    float*  outT = (float*)(ws + 12582912 + 25165824);      // 50,331,648 B
    int direct = (ws_size < (size_t)88080384) ? 1 : 0;

    ssm_kernel<<<192, 256, 0, stream>>>(Aang, Arad, B1p, B2p, C1p, C2p, k4);
    build_gf<<<768, 256, 0, stream>>>(k4, Gf);
    conv_fft<<<6144, 256, 0, stream>>>(x, Gf, omega, out, direct, outT);
    if (!direct) transpose_out<<<12288, 256, 0, stream>>>(outT, out);
}

// Round 2
// 283.612 us; speedup vs baseline: 1.4733x; 1.4733x over previous
//
#include <hip/hip_runtime.h>
#include <cmath>

#define PITCH 65
#define TWO_PI 6.283185307179586476925f

__device__ __forceinline__ float sigm(float v) { return 1.0f / (1.0f + expf(-v)); }

__device__ __forceinline__ float2 cmulf(float2 a, float2 b) {
    return make_float2(a.x * b.x - a.y * b.y, a.x * b.y + a.y * b.x);
}

__device__ __forceinline__ void dft4_fwd(float2& a0, float2& a1, float2& a2, float2& a3) {
    float t0r = a0.x + a2.x, t0i = a0.y + a2.y;
    float t1r = a0.x - a2.x, t1i = a0.y - a2.y;
    float t2r = a1.x + a3.x, t2i = a1.y + a3.y;
    float t3r = a1.x - a3.x, t3i = a1.y - a3.y;
    a0 = make_float2(t0r + t2r, t0i + t2i);
    a2 = make_float2(t0r - t2r, t0i - t2i);
    a1 = make_float2(t1r + t3i, t1i - t3r);
    a3 = make_float2(t1r - t3i, t1i + t3r);
}

__device__ __forceinline__ void dft4_inv(float2& a0, float2& a1, float2& a2, float2& a3) {
    float t0r = a0.x + a2.x, t0i = a0.y + a2.y;
    float t1r = a0.x - a2.x, t1i = a0.y - a2.y;
    float t2r = a1.x + a3.x, t2i = a1.y + a3.y;
    float t3r = a1.x - a3.x, t3i = a1.y - a3.y;
    a0 = make_float2(t0r + t2r, t0i + t2i);
    a2 = make_float2(t0r - t2r, t0i - t2i);
    a1 = make_float2(t1r - t3i, t1i + t3r);
    a3 = make_float2(t1r + t3i, t1i - t3r);
}

template<bool INV, bool COL>
__device__ void fft_pass(float2* a, const float2* tw, int tid, int lineLimit) {
#pragma unroll
    for (int si = 0; si < 3; ++si) {
        const int m = INV ? (4 << (2 * si)) : (64 >> (2 * si));
        const int q = m >> 2;
        __syncthreads();
#pragma unroll
        for (int k = 0; k < 4; ++k) {
            int beta = tid + 256 * k;
            int line = beta >> 4;
            int t = beta & 15;
            if (line < lineLimit) {
                int blk = t / q;
                int j = t - blk * q;
                int base = blk * m + j;
                int p0 = base, p1 = base + q, p2 = base + 2 * q, p3 = base + 3 * q;
                int e1 = j * (64 / m);
                int a0i = COL ? p0 * PITCH + line : line * PITCH + p0;
                int a1i = COL ? p1 * PITCH + line : line * PITCH + p1;
                int a2i = COL ? p2 * PITCH + line : line * PITCH + p2;
                int a3i = COL ? p3 * PITCH + line : line * PITCH + p3;
                float2 a0 = a[a0i], a1 = a[a1i], a2 = a[a2i], a3 = a[a3i];
                if (INV) {
                    float2 w1 = tw[e1], w2 = tw[2 * e1], w3 = tw[3 * e1];
                    w1.y = -w1.y; w2.y = -w2.y; w3.y = -w3.y;
                    a1 = cmulf(a1, w1); a2 = cmulf(a2, w2); a3 = cmulf(a3, w3);
                    dft4_inv(a0, a1, a2, a3);
                } else {
                    dft4_fwd(a0, a1, a2, a3);
                    a1 = cmulf(a1, tw[e1]);
                    a2 = cmulf(a2, tw[2 * e1]);
                    a3 = cmulf(a3, tw[3 * e1]);
                }
                a[a0i] = a0; a[a1i] = a1; a[a2i] = a2; a[a3i] = a3;
            }
        }
    }
    __syncthreads();
}

// ---------------- P1: 2-D SSM impulse response --------------------------------
// One WAVE per channel c. lane = jg + 4*n: n in [0,16) state dim, jg in [0,4)
// owns columns [8*jg, 8*jg+8). Horizontal recurrence solved per row with a
// 4-lane Kogge-Stone scan of linear maps (A1^8, d_t); n-reduced via shfl_xor.
__global__ __launch_bounds__(256) void ssm_kernel(
        const float* __restrict__ Aang, const float* __restrict__ Arad,
        const float* __restrict__ B1p, const float* __restrict__ B2p,
        const float* __restrict__ C1p, const float* __restrict__ C2p,
        float* __restrict__ k4) {
    int c = (blockIdx.x << 2) + (threadIdx.x >> 6);   // channel 0..3071
    int lane = threadIdx.x & 63;
    int jg = lane & 3;
    int n = lane >> 2;
    int gid = c * 16 + n;

    float ar[4], ai[4];
#pragma unroll
    for (int t = 0; t < 4; ++t) {
        float ang = sigm(Aang[t * 49152 + gid]) * TWO_PI;
        float rad = sigm(Arad[t * 49152 + gid]);
        float s, co;
        sincosf(ang, &s, &co);
        ar[t] = rad * co; ai[t] = rad * s;
    }
    float a1r = ar[0], a1i = ai[0], a2r = ar[1], a2i = ai[1];
    float a3r = ar[2], a3i = ai[2], a4r = ar[3], a4i = ai[3];
    // A1^8 (for the segment-composition scan)
    float p2r = a1r * a1r - a1i * a1i, p2i = 2.f * a1r * a1i;
    float p4r = p2r * p2r - p2i * p2i, p4i = 2.f * p2r * p2i;
    float p8r = p4r * p4r - p4i * p4i, p8i = 2.f * p4r * p4i;

    const float2* B1v = (const float2*)B1p;
    const float2* B2v = (const float2*)B2p;
    const float2* C1v = (const float2*)C1p;
    const float2* C2v = (const float2*)C2p;
    float2 b1 = B1v[gid], b2 = B2v[gid], c1 = C1v[gid], c2 = C2v[gid];
    float b1r = sigm(b1.x), b1i = sigm(b1.y);
    float b2r = sigm(b2.x), b2i = sigm(b2.y);
    float c1r = c1.x, c1i = c1.y, c2r = c2.x, c2i = c2.y;

    float xhr[8], xhi[8], xvr[8], xvi[8];
#pragma unroll
    for (int m = 0; m < 8; ++m) { xhr[m] = 0.f; xhi[m] = 0.f; xvr[m] = 0.f; xvi[m] = 0.f; }

    float* kout = k4 + c * 1024;
    for (int i = 0; i < 32; ++i) {
        // vertical: xv[i,j] = A3*xh[i-1,j] + A4*xv[i-1,j]
#pragma unroll
        for (int m = 0; m < 8; ++m) {
            float nr = a3r * xhr[m] - a3i * xhi[m] + a4r * xvr[m] - a4i * xvi[m];
            float ni = a3r * xhi[m] + a3i * xhr[m] + a4r * xvi[m] + a4i * xvr[m];
            xvr[m] = nr; xvi[m] = ni;
        }
        if (i == 0 && jg == 0) { xvr[0] += b2r; xvi[0] += b2i; }

        // segment load term d = sum_{m=0}^{7} A1^{7-m} * (A2 * xv[m])
        float cr = 0.f, ci = 0.f;
#pragma unroll
        for (int m = 0; m < 8; ++m) {
            float t = a1r * cr - a1i * ci + a2r * xvr[m] - a2i * xvi[m];
            ci = a1r * ci + a1i * cr + a2r * xvi[m] + a2i * xvr[m];
            cr = t;
        }
        // Kogge-Stone inclusive scan over jg of f_t(e) = A1^8 * e + d_t
        float Pr = p8r, Pi = p8i, Vr = cr, Vi = ci;
#pragma unroll
        for (int o = 1; o <= 2; o <<= 1) {
            int src = (jg >= o) ? (lane - o) : lane;
            float Pr2 = __shfl(Pr, src, 64);
            float Pi2 = __shfl(Pi, src, 64);
            float Vr2 = __shfl(Vr, src, 64);
            float Vi2 = __shfl(Vi, src, 64);
            if (jg >= o) {
                float nPr = Pr * Pr2 - Pi * Pi2;
                float nPi = Pr * Pi2 + Pi * Pr2;
                float nVr = Pr * Vr2 - Pi * Vi2 + Vr;
                float nVi = Pr * Vi2 + Pi * Vr2 + Vi;
                Pr = nPr; Pi = nPi; Vr = nVr; Vi = nVi;
            }
        }
        // entry value e_t = xh[i, 8*jg] from lane-1's inclusive map applied to h0
        int srcp = (jg >= 1) ? (lane - 1) : lane;
        float Ppr = __shfl(Pr, srcp, 64);
        float Ppi = __shfl(Pi, srcp, 64);
        float Vpr = __shfl(Vr, srcp, 64);
        float Vpi = __shfl(Vi, srcp, 64);
        float h0r = (i == 0) ? b1r : 0.f, h0i = (i == 0) ? b1i : 0.f;
        float er, ei;
        if (jg == 0) { er = h0r; ei = h0i; }
        else {
            er = Ppr * h0r - Ppi * h0i + Vpr;
            ei = Ppr * h0i + Ppi * h0r + Vpi;
        }
        // horizontal fill within segment
        xhr[0] = er; xhi[0] = ei;
        float gr = er, gi = ei;
#pragma unroll
        for (int m = 1; m < 8; ++m) {
            float t = a1r * gr - a1i * gi + a2r * xvr[m - 1] - a2i * xvi[m - 1];
            gi = a1r * gi + a1i * gr + a2r * xvi[m - 1] + a2i * xvr[m - 1];
            gr = t; xhr[m] = gr; xhi[m] = gi;
        }
        // output contribution + n-reduction
        float vals[8];
#pragma unroll
        for (int m = 0; m < 8; ++m) {
            float val = c1r * xhr[m] - c1i * xhi[m] + c2r * xvr[m] - c2i * xvi[m];
            val += __shfl_xor(val, 4, 64);
            val += __shfl_xor(val, 8, 64);
            val += __shfl_xor(val, 16, 64);
            val += __shfl_xor(val, 32, 64);
            vals[m] = val;
        }
        if (n == 0) {
            float fi = (i == 0) ? 2.f : 1.f;
            float f0 = (jg == 0) ? ((i == 0) ? 1.f : 2.f) : fi;
            float4 v0, v1;
            v0.x = 0.25f * f0 * vals[0];
            v0.y = 0.25f * fi * vals[1];
            v0.z = 0.25f * fi * vals[2];
            v0.w = 0.25f * fi * vals[3];
            v1.x = 0.25f * fi * vals[4];
            v1.y = 0.25f * fi * vals[5];
            v1.z = 0.25f * fi * vals[6];
            v1.w = 0.25f * fi * vals[7];
            float4* dst = (float4*)(kout + i * 32 + 8 * jg);
            dst[0] = v0; dst[1] = v1;
        }
    }
}

// ---------------- P2: combined-direction kernel -> spectrum -------------------
__global__ __launch_bounds__(256) void build_gf(const float* __restrict__ k4,
                                                float2* __restrict__ Gf) {
    __shared__ float2 a[64 * PITCH];
    __shared__ float2 tw[64];
    int d = blockIdx.x, tid = threadIdx.x;
    for (int e = tid; e < 64 * PITCH; e += 256) a[e] = make_float2(0.f, 0.f);
    if (tid < 64) {
        float s, co;
        sincosf(-TWO_PI * (float)tid / 64.0f, &s, &co);
        tw[tid] = make_float2(co, s);
    }
    __syncthreads();
#pragma unroll
    for (int k = 0; k < 4; ++k) {
        int cell = tid + 256 * k;
        int p = cell >> 5, q = cell & 31;
        float k0 = k4[(0 * 768 + d) * 1024 + cell];
        float k1 = k4[(1 * 768 + d) * 1024 + cell];
        float k2 = k4[(2 * 768 + d) * 1024 + cell];
        float k3 = k4[(3 * 768 + d) * 1024 + cell];
        int pn = (64 - p) & 63, qn = (64 - q) & 63;
        a[p  * PITCH + q ].x += k0;
        a[pn * PITCH + q ].x += k1;
        a[p  * PITCH + qn].x += k2;
        a[pn * PITCH + qn].x += k3;
    }
    fft_pass<false, false>(a, tw, tid, 64);
    fft_pass<false, true >(a, tw, tid, 64);
    for (int e = tid; e < 4096; e += 256) {
        int u = e >> 6, v = e & 63;
        Gf[d * 4096 + e] = a[u * PITCH + v];
    }
}

// ---------------- P3: FFT conv, two batch images packed re/im -----------------
__global__ __launch_bounds__(256) void conv_fft(
        const float* __restrict__ x, const float2* __restrict__ Gf,
        const float* __restrict__ omega, float* __restrict__ out,
        int directOut, float* __restrict__ outT) {
    __shared__ float2 a[64 * PITCH];
    __shared__ float2 tw[64];
    int bid = blockIdx.x;
    int d = bid >> 3, b = (bid & 7) * 2;
    int tid = threadIdx.x;

    for (int e = tid; e < 64 * PITCH; e += 256) a[e] = make_float2(0.f, 0.f);
    if (tid < 64) {
        float s, co;
        sincosf(-TWO_PI * (float)tid / 64.0f, &s, &co);
        tw[tid] = make_float2(co, s);
    }
    __syncthreads();
    for (int s = tid; s < 1024; s += 256) {
        float xa = x[s * 12288 + b * 768 + d];
        float xb = x[s * 12288 + (b + 1) * 768 + d];
        a[(s >> 5) * PITCH + (s & 31)] = make_float2(xa, xb);
    }
    fft_pass<false, false>(a, tw, tid, 32);   // fwd rows (rows 32..63 zero)
    fft_pass<false, true >(a, tw, tid, 64);   // fwd cols
    for (int e = tid; e < 4096; e += 256) {
        int u = e >> 6, v = e & 63;
        a[u * PITCH + v] = cmulf(a[u * PITCH + v], Gf[d * 4096 + e]);
    }
    fft_pass<true, true >(a, tw, tid, 64);    // inv cols
    fft_pass<true, false>(a, tw, tid, 32);    // inv rows (only 0..31 needed)

    float w = omega[d];
    const float inv = 1.0f / 4096.0f;
    for (int s = tid; s < 1024; s += 256) {
        float2 cc = a[(s >> 5) * PITCH + (s & 31)];
        float xa = x[s * 12288 + b * 768 + d];
        float xb = x[s * 12288 + (b + 1) * 768 + d];
        float ya = cc.x * inv + xa * w;
        float yb = cc.y * inv + xb * w;
        float oa = ya / (1.0f + expf(-ya));
        float ob = yb / (1.0f + expf(-yb));
        if (directOut) {
            out[s * 12288 + b * 768 + d] = oa;
            out[s * 12288 + (b + 1) * 768 + d] = ob;
        } else {
            outT[(b * 768 + d) * 1024 + s] = oa;
            outT[((b + 1) * 768 + d) * 1024 + s] = ob;
        }
    }
}

// ---------------- P4: (B*D, S) -> (S, B*D) transpose --------------------------
__global__ __launch_bounds__(256) void transpose_out(const float* __restrict__ outT,
                                                     float* __restrict__ out) {
    __shared__ float t[32][33];
    int bR = blockIdx.x % 384, bS = blockIdx.x / 384;
    int r0 = bR * 32, s0 = bS * 32;
    int tx = threadIdx.x & 31, ty = threadIdx.x >> 5;
#pragma unroll
    for (int k = 0; k < 4; ++k) {
        int r = ty + 8 * k;
        t[r][tx] = outT[(r0 + r) * 1024 + s0 + tx];
    }
    __syncthreads();
#pragma unroll
    for (int k = 0; k < 4; ++k) {
        int r = ty + 8 * k;
        out[(s0 + r) * 12288 + r0 + tx] = t[tx][r];
    }
}

extern "C" void kernel_launch(void* const* d_in, const int* in_sizes, int n_in,
                              void* d_out, int out_size, void* d_ws, size_t ws_size,
                              hipStream_t stream) {
    const float* x     = (const float*)d_in[0];
    const float* Aang  = (const float*)d_in[1];
    const float* Arad  = (const float*)d_in[2];
    const float* B1p   = (const float*)d_in[3];
    const float* B2p   = (const float*)d_in[4];
    const float* C1p   = (const float*)d_in[5];
    const float* C2p   = (const float*)d_in[6];
    const float* omega = (const float*)d_in[7];
    float* out = (float*)d_out;
    char* ws = (char*)d_ws;

    float*  k4   = (float*)ws;                              // 12,582,912 B
    float2* Gf   = (float2*)(ws + 12582912);                // 25,165,824 B
    float*  outT = (float*)(ws + 12582912 + 25165824);      // 50,331,648 B
    int direct = (ws_size < (size_t)88080384) ? 1 : 0;

    ssm_kernel<<<768, 256, 0, stream>>>(Aang, Arad, B1p, B2p, C1p, C2p, k4);
    build_gf<<<768, 256, 0, stream>>>(k4, Gf);
    conv_fft<<<6144, 256, 0, stream>>>(x, Gf, omega, out, direct, outT);
    if (!direct) transpose_out<<<12288, 256, 0, stream>>>(outT, out);
}

// Round 3
// 256.267 us; speedup vs baseline: 1.6305x; 1.1067x over previous
//
#include <hip/hip_runtime.h>
#include <cmath>

#define TWO_PI 6.283185307179586476925f

__device__ __forceinline__ float sigm(float v) { return 1.0f / (1.0f + expf(-v)); }

__device__ __forceinline__ float2 cmulf(float2 a, float2 b) {
    return make_float2(a.x * b.x - a.y * b.y, a.x * b.y + a.y * b.x);
}
__device__ __forceinline__ float2 conjf(float2 a) { return make_float2(a.x, -a.y); }

// Swizzled physical index for a 64x64 float2 LDS array.
// phys = r*64 + (c ^ (c>>2) ^ ((r ^ (r>>2)) & 15)): bank-conflict-free for all
// radix-4 stage access sets ({t},{16b+j},{4t}+shifts) in BOTH orientations.
__device__ __forceinline__ int swidx(int r, int c) {
    return (r << 6) | (c ^ (c >> 2) ^ ((r ^ (r >> 2)) & 15));
}

__device__ __forceinline__ void dft4_fwd(float2& a0, float2& a1, float2& a2, float2& a3) {
    float t0r = a0.x + a2.x, t0i = a0.y + a2.y;
    float t1r = a0.x - a2.x, t1i = a0.y - a2.y;
    float t2r = a1.x + a3.x, t2i = a1.y + a3.y;
    float t3r = a1.x - a3.x, t3i = a1.y - a3.y;
    a0 = make_float2(t0r + t2r, t0i + t2i);
    a2 = make_float2(t0r - t2r, t0i - t2i);
    a1 = make_float2(t1r + t3i, t1i - t3r);
    a3 = make_float2(t1r - t3i, t1i + t3r);
}

__device__ __forceinline__ void dft4_inv(float2& a0, float2& a1, float2& a2, float2& a3) {
    float t0r = a0.x + a2.x, t0i = a0.y + a2.y;
    float t1r = a0.x - a2.x, t1i = a0.y - a2.y;
    float t2r = a1.x + a3.x, t2i = a1.y + a3.y;
    float t3r = a1.x - a3.x, t3i = a1.y - a3.y;
    a0 = make_float2(t0r + t2r, t0i + t2i);
    a2 = make_float2(t0r - t2r, t0i - t2i);
    a1 = make_float2(t1r - t3i, t1i + t3r);
    a3 = make_float2(t1r + t3i, t1i - t3r);
}

template<bool INV, bool TRIV>
__device__ __forceinline__ void bfly(float2* a, int i0, int i1, int i2, int i3,
                                     float2 w1, float2 w2, float2 w3) {
    float2 a0 = a[i0], a1 = a[i1], a2 = a[i2], a3 = a[i3];
    if (INV) {
        if (!TRIV) { a1 = cmulf(a1, w1); a2 = cmulf(a2, w2); a3 = cmulf(a3, w3); }
        dft4_inv(a0, a1, a2, a3);
    } else {
        dft4_fwd(a0, a1, a2, a3);
        if (!TRIV) { a1 = cmulf(a1, w1); a2 = cmulf(a2, w2); a3 = cmulf(a3, w3); }
    }
    a[i0] = a0; a[i1] = a1; a[i2] = a2; a[i3] = a3;
}

template<bool INV, bool COL, int LINES, bool TRIV>
__device__ __forceinline__ void fft_stage(float2* a, int l0,
        int p0, int p1, int p2, int p3, float2 tw1, float2 tw2, float2 tw3) {
    __syncthreads();
#pragma unroll
    for (int k = 0; k < LINES / 16; ++k) {
        int line = l0 + 16 * k;
        int i0 = COL ? swidx(p0, line) : swidx(line, p0);
        int i1 = COL ? swidx(p1, line) : swidx(line, p1);
        int i2 = COL ? swidx(p2, line) : swidx(line, p2);
        int i3 = COL ? swidx(p3, line) : swidx(line, p3);
        bfly<INV, TRIV>(a, i0, i1, i2, i3, tw1, tw2, tw3);
    }
}

// Forward: DIF natural -> digit-reversed. Inverse: exact stage reversal,
// digit-reversed -> natural (unnormalized; 2D total scale 4096).
// Leading __syncthreads() per stage; callers barrier before consuming results.
template<bool INV, bool COL, int LINES>
__device__ __forceinline__ void fft_pass(float2* a, int tid,
        float2 w1, float2 w2, float2 w3, float2 u1, float2 u2, float2 u3) {
    const int t = tid & 15;
    const int l0 = tid >> 4;
    const int bb = ((t >> 2) << 4) | (t & 3);
    const float2 one = make_float2(1.f, 0.f);
    if (!INV) {
        fft_stage<INV, COL, LINES, false>(a, l0, t, t + 16, t + 32, t + 48, w1, w2, w3);
        fft_stage<INV, COL, LINES, false>(a, l0, bb, bb + 4, bb + 8, bb + 12, u1, u2, u3);
        fft_stage<INV, COL, LINES, true >(a, l0, 4 * t, 4 * t + 1, 4 * t + 2, 4 * t + 3, one, one, one);
    } else {
        fft_stage<INV, COL, LINES, true >(a, l0, 4 * t, 4 * t + 1, 4 * t + 2, 4 * t + 3, one, one, one);
        fft_stage<INV, COL, LINES, false>(a, l0, bb, bb + 4, bb + 8, bb + 12, u1, u2, u3);
        fft_stage<INV, COL, LINES, false>(a, l0, t, t + 16, t + 32, t + 48, w1, w2, w3);
    }
}

// ---------------- P1: 2-D SSM impulse response --------------------------------
// One WAVE per channel c. lane = jg + 4*n: n in [0,16) state dim, jg in [0,4)
// owns columns [8*jg, 8*jg+8). Horizontal recurrence solved per row with a
// 4-lane Kogge-Stone scan of linear maps (A1^8, d_t); n-reduced via shfl_xor.
__global__ __launch_bounds__(256) void ssm_kernel(
        const float* __restrict__ Aang, const float* __restrict__ Arad,
        const float* __restrict__ B1p, const float* __restrict__ B2p,
        const float* __restrict__ C1p, const float* __restrict__ C2p,
        float* __restrict__ k4) {
    int c = (blockIdx.x << 2) + (threadIdx.x >> 6);
    int lane = threadIdx.x & 63;
    int jg = lane & 3;
    int n = lane >> 2;
    int gid = c * 16 + n;

    float ar[4], ai[4];
#pragma unroll
    for (int t = 0; t < 4; ++t) {
        float ang = sigm(Aang[t * 49152 + gid]) * TWO_PI;
        float rad = sigm(Arad[t * 49152 + gid]);
        float s, co;
        sincosf(ang, &s, &co);
        ar[t] = rad * co; ai[t] = rad * s;
    }
    float a1r = ar[0], a1i = ai[0], a2r = ar[1], a2i = ai[1];
    float a3r = ar[2], a3i = ai[2], a4r = ar[3], a4i = ai[3];
    float p2r = a1r * a1r - a1i * a1i, p2i = 2.f * a1r * a1i;
    float p4r = p2r * p2r - p2i * p2i, p4i = 2.f * p2r * p2i;
    float p8r = p4r * p4r - p4i * p4i, p8i = 2.f * p4r * p4i;

    const float2* B1v = (const float2*)B1p;
    const float2* B2v = (const float2*)B2p;
    const float2* C1v = (const float2*)C1p;
    const float2* C2v = (const float2*)C2p;
    float2 b1 = B1v[gid], b2 = B2v[gid], c1 = C1v[gid], c2 = C2v[gid];
    float b1r = sigm(b1.x), b1i = sigm(b1.y);
    float b2r = sigm(b2.x), b2i = sigm(b2.y);
    float c1r = c1.x, c1i = c1.y, c2r = c2.x, c2i = c2.y;

    float xhr[8], xhi[8], xvr[8], xvi[8];
#pragma unroll
    for (int m = 0; m < 8; ++m) { xhr[m] = 0.f; xhi[m] = 0.f; xvr[m] = 0.f; xvi[m] = 0.f; }

    float* kout = k4 + c * 1024;
    for (int i = 0; i < 32; ++i) {
#pragma unroll
        for (int m = 0; m < 8; ++m) {
            float nr = a3r * xhr[m] - a3i * xhi[m] + a4r * xvr[m] - a4i * xvi[m];
            float ni = a3r * xhi[m] + a3i * xhr[m] + a4r * xvi[m] + a4i * xvr[m];
            xvr[m] = nr; xvi[m] = ni;
        }
        if (i == 0 && jg == 0) { xvr[0] += b2r; xvi[0] += b2i; }

        float cr = 0.f, ci = 0.f;
#pragma unroll
        for (int m = 0; m < 8; ++m) {
            float t = a1r * cr - a1i * ci + a2r * xvr[m] - a2i * xvi[m];
            ci = a1r * ci + a1i * cr + a2r * xvi[m] + a2i * xvr[m];
            cr = t;
        }
        float Pr = p8r, Pi = p8i, Vr = cr, Vi = ci;
#pragma unroll
        for (int o = 1; o <= 2; o <<= 1) {
            int src = (jg >= o) ? (lane - o) : lane;
            float Pr2 = __shfl(Pr, src, 64);
            float Pi2 = __shfl(Pi, src, 64);
            float Vr2 = __shfl(Vr, src, 64);
            float Vi2 = __shfl(Vi, src, 64);
            if (jg >= o) {
                float nPr = Pr * Pr2 - Pi * Pi2;
                float nPi = Pr * Pi2 + Pi * Pr2;
                float nVr = Pr * Vr2 - Pi * Vi2 + Vr;
                float nVi = Pr * Vi2 + Pi * Vr2 + Vi;
                Pr = nPr; Pi = nPi; Vr = nVr; Vi = nVi;
            }
        }
        int srcp = (jg >= 1) ? (lane - 1) : lane;
        float Ppr = __shfl(Pr, srcp, 64);
        float Ppi = __shfl(Pi, srcp, 64);
        float Vpr = __shfl(Vr, srcp, 64);
        float Vpi = __shfl(Vi, srcp, 64);
        float h0r = (i == 0) ? b1r : 0.f, h0i = (i == 0) ? b1i : 0.f;
        float er, ei;
        if (jg == 0) { er = h0r; ei = h0i; }
        else {
            er = Ppr * h0r - Ppi * h0i + Vpr;
            ei = Ppr * h0i + Ppi * h0r + Vpi;
        }
        xhr[0] = er; xhi[0] = ei;
        float gr = er, gi = ei;
#pragma unroll
        for (int m = 1; m < 8; ++m) {
            float t = a1r * gr - a1i * gi + a2r * xvr[m - 1] - a2i * xvi[m - 1];
            gi = a1r * gi + a1i * gr + a2r * xvi[m - 1] + a2i * xvr[m - 1];
            gr = t; xhr[m] = gr; xhi[m] = gi;
        }
        float vals[8];
#pragma unroll
        for (int m = 0; m < 8; ++m) {
            float val = c1r * xhr[m] - c1i * xhi[m] + c2r * xvr[m] - c2i * xvi[m];
            val += __shfl_xor(val, 4, 64);
            val += __shfl_xor(val, 8, 64);
            val += __shfl_xor(val, 16, 64);
            val += __shfl_xor(val, 32, 64);
            vals[m] = val;
        }
        if (n == 0) {
            float fi = (i == 0) ? 2.f : 1.f;
            float f0 = (jg == 0) ? ((i == 0) ? 1.f : 2.f) : fi;
            float4 v0, v1;
            v0.x = 0.25f * f0 * vals[0];
            v0.y = 0.25f * fi * vals[1];
            v0.z = 0.25f * fi * vals[2];
            v0.w = 0.25f * fi * vals[3];
            v1.x = 0.25f * fi * vals[4];
            v1.y = 0.25f * fi * vals[5];
            v1.z = 0.25f * fi * vals[6];
            v1.w = 0.25f * fi * vals[7];
            float4* dst = (float4*)(kout + i * 32 + 8 * jg);
            dst[0] = v0; dst[1] = v1;
        }
    }
}

// ---------------- P2: combined-direction kernel -> spectrum -------------------
__global__ __launch_bounds__(256) void build_gf(const float* __restrict__ k4,
                                                float2* __restrict__ Gf) {
    __shared__ float2 a[4096];
    int d = blockIdx.x, tid = threadIdx.x;
    int t = tid & 15;
    float s, co;
    sincosf(-TWO_PI * (float)t / 64.f, &s, &co);
    float2 w1 = make_float2(co, s);
    float2 w2 = cmulf(w1, w1), w3 = cmulf(w2, w1);
    sincosf(-TWO_PI * (float)((t & 3) * 4) / 64.f, &s, &co);
    float2 u1 = make_float2(co, s);
    float2 u2 = cmulf(u1, u1), u3 = cmulf(u2, u1);

    for (int e = tid; e < 4096; e += 256) a[e] = make_float2(0.f, 0.f);
    __syncthreads();
#pragma unroll
    for (int k = 0; k < 4; ++k) {
        int cell = tid + 256 * k;
        int p = cell >> 5, q = cell & 31;
        float k0 = k4[(0 * 768 + d) * 1024 + cell];
        float k1 = k4[(1 * 768 + d) * 1024 + cell];
        float k2 = k4[(2 * 768 + d) * 1024 + cell];
        float k3 = k4[(3 * 768 + d) * 1024 + cell];
        int pn = (64 - p) & 63, qn = (64 - q) & 63;
        a[swidx(p,  q )].x += k0;
        a[swidx(pn, q )].x += k1;
        a[swidx(p,  qn)].x += k2;
        a[swidx(pn, qn)].x += k3;
    }
    fft_pass<false, false, 64>(a, tid, w1, w2, w3, u1, u2, u3);
    fft_pass<false, true , 64>(a, tid, w1, w2, w3, u1, u2, u3);
    __syncthreads();
    for (int e = tid; e < 4096; e += 256) {
        Gf[d * 4096 + e] = a[swidx(e >> 6, e & 63)];
    }
}

// ---------------- P3: FFT conv, two batch images packed re/im -----------------
__global__ __launch_bounds__(256) void conv_fft(
        const float* __restrict__ x, const float2* __restrict__ Gf,
        const float* __restrict__ omega, float* __restrict__ out,
        int directOut, float* __restrict__ outT) {
    __shared__ float2 a[4096];
    int bid = blockIdx.x;
    int d = bid >> 3, b = (bid & 7) * 2;
    int tid = threadIdx.x;
    int t = tid & 15;
    float s, co;
    sincosf(-TWO_PI * (float)t / 64.f, &s, &co);
    float2 w1 = make_float2(co, s);
    float2 w2 = cmulf(w1, w1), w3 = cmulf(w2, w1);
    sincosf(-TWO_PI * (float)((t & 3) * 4) / 64.f, &s, &co);
    float2 u1 = make_float2(co, s);
    float2 u2 = cmulf(u1, u1), u3 = cmulf(u2, u1);
    float2 w1c = conjf(w1), w2c = conjf(w2), w3c = conjf(w3);
    float2 u1c = conjf(u1), u2c = conjf(u2), u3c = conjf(u3);

    // zero only the cells NOT covered by the (r<32, c<32) prologue writes:
    // for r<32,c<32 phys has bit11==0 and bit5==0 -> disjoint sets, no barrier.
    for (int e = tid; e < 4096; e += 256) {
        if ((e & 0x820) != 0) a[e] = make_float2(0.f, 0.f);
    }
    for (int s2 = tid; s2 < 1024; s2 += 256) {
        float xa = x[s2 * 12288 + b * 768 + d];
        float xb = x[s2 * 12288 + (b + 1) * 768 + d];
        a[swidx(s2 >> 5, s2 & 31)] = make_float2(xa, xb);
    }
    fft_pass<false, false, 32>(a, tid, w1, w2, w3, u1, u2, u3);   // fwd rows
    fft_pass<false, true , 64>(a, tid, w1, w2, w3, u1, u2, u3);   // fwd cols
    __syncthreads();
    for (int e = tid; e < 4096; e += 256) {
        int ii = swidx(e >> 6, e & 63);
        a[ii] = cmulf(a[ii], Gf[d * 4096 + e]);
    }
    fft_pass<true, true , 64>(a, tid, w1c, w2c, w3c, u1c, u2c, u3c);  // inv cols
    fft_pass<true, false, 32>(a, tid, w1c, w2c, w3c, u1c, u2c, u3c);  // inv rows
    __syncthreads();

    float w = omega[d];
    const float inv = 1.0f / 4096.0f;
    for (int s2 = tid; s2 < 1024; s2 += 256) {
        float2 cc = a[swidx(s2 >> 5, s2 & 31)];
        float xa = x[s2 * 12288 + b * 768 + d];
        float xb = x[s2 * 12288 + (b + 1) * 768 + d];
        float ya = cc.x * inv + xa * w;
        float yb = cc.y * inv + xb * w;
        float oa = ya / (1.0f + expf(-ya));
        float ob = yb / (1.0f + expf(-yb));
        if (directOut) {
            out[s2 * 12288 + b * 768 + d] = oa;
            out[s2 * 12288 + (b + 1) * 768 + d] = ob;
        } else {
            outT[(b * 768 + d) * 1024 + s2] = oa;
            outT[((b + 1) * 768 + d) * 1024 + s2] = ob;
        }
    }
}

// ---------------- P4: (B*D, S) -> (S, B*D) transpose --------------------------
__global__ __launch_bounds__(256) void transpose_out(const float* __restrict__ outT,
                                                     float* __restrict__ out) {
    __shared__ float t[32][33];
    int bR = blockIdx.x % 384, bS = blockIdx.x / 384;
    int r0 = bR * 32, s0 = bS * 32;
    int tx = threadIdx.x & 31, ty = threadIdx.x >> 5;
#pragma unroll
    for (int k = 0; k < 4; ++k) {
        int r = ty + 8 * k;
        t[r][tx] = outT[(r0 + r) * 1024 + s0 + tx];
    }
    __syncthreads();
#pragma unroll
    for (int k = 0; k < 4; ++k) {
        int r = ty + 8 * k;
        out[(s0 + r) * 12288 + r0 + tx] = t[tx][r];
    }
}

extern "C" void kernel_launch(void* const* d_in, const int* in_sizes, int n_in,
                              void* d_out, int out_size, void* d_ws, size_t ws_size,
                              hipStream_t stream) {
    const float* x     = (const float*)d_in[0];
    const float* Aang  = (const float*)d_in[1];
    const float* Arad  = (const float*)d_in[2];
    const float* B1p   = (const float*)d_in[3];
    const float* B2p   = (const float*)d_in[4];
    const float* C1p   = (const float*)d_in[5];
    const float* C2p   = (const float*)d_in[6];
    const float* omega = (const float*)d_in[7];
    float* out = (float*)d_out;
    char* ws = (char*)d_ws;

    float*  k4   = (float*)ws;                              // 12,582,912 B
    float2* Gf   = (float2*)(ws + 12582912);                // 25,165,824 B
    float*  outT = (float*)(ws + 12582912 + 25165824);      // 50,331,648 B
    int direct = (ws_size < (size_t)88080384) ? 1 : 0;

    ssm_kernel<<<768, 256, 0, stream>>>(Aang, Arad, B1p, B2p, C1p, C2p, k4);
    build_gf<<<768, 256, 0, stream>>>(k4, Gf);
    conv_fft<<<6144, 256, 0, stream>>>(x, Gf, omega, out, direct, outT);
    if (!direct) transpose_out<<<12288, 256, 0, stream>>>(outT, out);
}

// Round 4
// 241.870 us; speedup vs baseline: 1.7276x; 1.0595x over previous
//
#include <hip/hip_runtime.h>
#include <cmath>

#define TWO_PI 6.283185307179586476925f

__device__ __forceinline__ float sigm(float v) { return 1.0f / (1.0f + expf(-v)); }
__device__ __forceinline__ float2 cadd(float2 a, float2 b) { return make_float2(a.x + b.x, a.y + b.y); }
__device__ __forceinline__ float2 csub(float2 a, float2 b) { return make_float2(a.x - b.x, a.y - b.y); }
__device__ __forceinline__ float2 cmulf(float2 a, float2 b) {
    return make_float2(a.x * b.x - a.y * b.y, a.x * b.y + a.y * b.x);
}

// XOR-swizzled cell address for the 64x64 float2 tile.
// All pass access patterns give 64 distinct low-6 bits per wave access -> 2-way
// b64 aliasing = conflict-free minimum (verified per-phase bank algebra).
__device__ __forceinline__ int swz(int r, int c) {
    return (r << 6) | (c ^ ((r ^ (r << 3)) & 63));
}

// In-register 8-point DFT, natural-order outputs. INV = conj twiddles.
// HALF: inputs x[4..7] are known zero.
template<bool INV, bool HALF>
__device__ __forceinline__ void dft8(float2* x) {
    const float RS = 0.70710678118654752440f;
    float2 t0, t1, t2, t3, t4, t5, t6, t7;
    if (HALF) {
        t0 = x[0]; t4 = x[0]; t1 = x[1]; t5 = x[1];
        t2 = x[2]; t6 = x[2]; t3 = x[3]; t7 = x[3];
    } else {
        t0 = cadd(x[0], x[4]); t4 = csub(x[0], x[4]);
        t1 = cadd(x[1], x[5]); t5 = csub(x[1], x[5]);
        t2 = cadd(x[2], x[6]); t6 = csub(x[2], x[6]);
        t3 = cadd(x[3], x[7]); t7 = csub(x[3], x[7]);
    }
    float2 t5w, t6w, t7w;
    if (!INV) {
        t5w = make_float2(RS * (t5.x + t5.y), RS * (t5.y - t5.x));   // *W8^1
        t6w = make_float2(t6.y, -t6.x);                               // *W8^2 = -i
        t7w = make_float2(RS * (t7.y - t7.x), -RS * (t7.x + t7.y));   // *W8^3
    } else {
        t5w = make_float2(RS * (t5.x - t5.y), RS * (t5.y + t5.x));    // *W8^-1
        t6w = make_float2(-t6.y, t6.x);                               // *W8^-2 = i
        t7w = make_float2(-RS * (t7.x + t7.y), RS * (t7.x - t7.y));   // *W8^-3
    }
    float2 u0 = cadd(t0, t2), u2 = csub(t0, t2), u1 = cadd(t1, t3), dd = csub(t1, t3);
    float2 u3 = INV ? make_float2(-dd.y, dd.x) : make_float2(dd.y, -dd.x);
    x[0] = cadd(u0, u1); x[4] = csub(u0, u1); x[2] = cadd(u2, u3); x[6] = csub(u2, u3);
    float2 v0 = cadd(t4, t6w), v2 = csub(t4, t6w), v1 = cadd(t5w, t7w), ee = csub(t5w, t7w);
    float2 v3 = INV ? make_float2(-ee.y, ee.x) : make_float2(ee.y, -ee.x);
    x[1] = cadd(v0, v1); x[5] = csub(v0, v1); x[3] = cadd(v2, v3); x[7] = csub(v2, v3);
}

// 64-pt FFT over one line by an 8-lane group. Input: reg j = point (8j+o).
// Output: reg m = point (o+8m). Natural frequency order. Uses the line's own
// cells as transpose scratch (group-private; within-wave LDS is ordered).
// tw[k-1] = W64^{-o*k} (forward twiddles); INV uses conj.
template<bool INV, bool COL, bool HALF>
__device__ __forceinline__ void fft64(float2* a, float2* r, const float2* tw,
                                      int o, int line) {
    dft8<INV, HALF>(r);
#pragma unroll
    for (int k = 1; k < 8; ++k) {
        float2 w = tw[k - 1];
        if (INV) w.y = -w.y;
        r[k] = cmulf(r[k], w);
    }
#pragma unroll
    for (int m = 0; m < 8; ++m) {
        int s = 8 * o + m;
        a[COL ? swz(s, line) : swz(line, s)] = r[m];
    }
#pragma unroll
    for (int j = 0; j < 8; ++j) {
        int s = 8 * j + o;
        r[j] = a[COL ? swz(s, line) : swz(line, s)];
    }
    dft8<INV, false>(r);
}

// ---------------- P1: 2-D SSM impulse response --------------------------------
// One WAVE per channel c. lane = jg + 4*n: n in [0,16) state dim, jg in [0,4)
// owns columns [8*jg, 8*jg+8). Horizontal recurrence solved per row with a
// 4-lane Kogge-Stone scan of linear maps (A1^8, d_t); n-reduced via shfl_xor.
__global__ __launch_bounds__(256) void ssm_kernel(
        const float* __restrict__ Aang, const float* __restrict__ Arad,
        const float* __restrict__ B1p, const float* __restrict__ B2p,
        const float* __restrict__ C1p, const float* __restrict__ C2p,
        float* __restrict__ k4) {
    int c = (blockIdx.x << 2) + (threadIdx.x >> 6);
    int lane = threadIdx.x & 63;
    int jg = lane & 3;
    int n = lane >> 2;
    int gid = c * 16 + n;

    float ar[4], ai[4];
#pragma unroll
    for (int t = 0; t < 4; ++t) {
        float ang = sigm(Aang[t * 49152 + gid]) * TWO_PI;
        float rad = sigm(Arad[t * 49152 + gid]);
        float s, co;
        sincosf(ang, &s, &co);
        ar[t] = rad * co; ai[t] = rad * s;
    }
    float a1r = ar[0], a1i = ai[0], a2r = ar[1], a2i = ai[1];
    float a3r = ar[2], a3i = ai[2], a4r = ar[3], a4i = ai[3];
    float p2r = a1r * a1r - a1i * a1i, p2i = 2.f * a1r * a1i;
    float p4r = p2r * p2r - p2i * p2i, p4i = 2.f * p2r * p2i;
    float p8r = p4r * p4r - p4i * p4i, p8i = 2.f * p4r * p4i;

    const float2* B1v = (const float2*)B1p;
    const float2* B2v = (const float2*)B2p;
    const float2* C1v = (const float2*)C1p;
    const float2* C2v = (const float2*)C2p;
    float2 b1 = B1v[gid], b2 = B2v[gid], c1 = C1v[gid], c2 = C2v[gid];
    float b1r = sigm(b1.x), b1i = sigm(b1.y);
    float b2r = sigm(b2.x), b2i = sigm(b2.y);
    float c1r = c1.x, c1i = c1.y, c2r = c2.x, c2i = c2.y;

    float xhr[8], xhi[8], xvr[8], xvi[8];
#pragma unroll
    for (int m = 0; m < 8; ++m) { xhr[m] = 0.f; xhi[m] = 0.f; xvr[m] = 0.f; xvi[m] = 0.f; }

    float* kout = k4 + c * 1024;
    for (int i = 0; i < 32; ++i) {
#pragma unroll
        for (int m = 0; m < 8; ++m) {
            float nr = a3r * xhr[m] - a3i * xhi[m] + a4r * xvr[m] - a4i * xvi[m];
            float ni = a3r * xhi[m] + a3i * xhr[m] + a4r * xvi[m] + a4i * xvr[m];
            xvr[m] = nr; xvi[m] = ni;
        }
        if (i == 0 && jg == 0) { xvr[0] += b2r; xvi[0] += b2i; }

        float cr = 0.f, ci = 0.f;
#pragma unroll
        for (int m = 0; m < 8; ++m) {
            float t = a1r * cr - a1i * ci + a2r * xvr[m] - a2i * xvi[m];
            ci = a1r * ci + a1i * cr + a2r * xvi[m] + a2i * xvr[m];
            cr = t;
        }
        float Pr = p8r, Pi = p8i, Vr = cr, Vi = ci;
#pragma unroll
        for (int o = 1; o <= 2; o <<= 1) {
            int src = (jg >= o) ? (lane - o) : lane;
            float Pr2 = __shfl(Pr, src, 64);
            float Pi2 = __shfl(Pi, src, 64);
            float Vr2 = __shfl(Vr, src, 64);
            float Vi2 = __shfl(Vi, src, 64);
            if (jg >= o) {
                float nPr = Pr * Pr2 - Pi * Pi2;
                float nPi = Pr * Pi2 + Pi * Pr2;
                float nVr = Pr * Vr2 - Pi * Vi2 + Vr;
                float nVi = Pr * Vi2 + Pi * Vr2 + Vi;
                Pr = nPr; Pi = nPi; Vr = nVr; Vi = nVi;
            }
        }
        int srcp = (jg >= 1) ? (lane - 1) : lane;
        float Ppr = __shfl(Pr, srcp, 64);
        float Ppi = __shfl(Pi, srcp, 64);
        float Vpr = __shfl(Vr, srcp, 64);
        float Vpi = __shfl(Vi, srcp, 64);
        float h0r = (i == 0) ? b1r : 0.f, h0i = (i == 0) ? b1i : 0.f;
        float er, ei;
        if (jg == 0) { er = h0r; ei = h0i; }
        else {
            er = Ppr * h0r - Ppi * h0i + Vpr;
            ei = Ppr * h0i + Ppi * h0r + Vpi;
        }
        xhr[0] = er; xhi[0] = ei;
        float gr = er, gi = ei;
#pragma unroll
        for (int m = 1; m < 8; ++m) {
            float t = a1r * gr - a1i * gi + a2r * xvr[m - 1] - a2i * xvi[m - 1];
            gi = a1r * gi + a1i * gr + a2r * xvi[m - 1] + a2i * xvr[m - 1];
            gr = t; xhr[m] = gr; xhi[m] = gi;
        }
        float vals[8];
#pragma unroll
        for (int m = 0; m < 8; ++m) {
            float val = c1r * xhr[m] - c1i * xhi[m] + c2r * xvr[m] - c2i * xvi[m];
            val += __shfl_xor(val, 4, 64);
            val += __shfl_xor(val, 8, 64);
            val += __shfl_xor(val, 16, 64);
            val += __shfl_xor(val, 32, 64);
            vals[m] = val;
        }
        if (n == 0) {
            float fi = (i == 0) ? 2.f : 1.f;
            float f0 = (jg == 0) ? ((i == 0) ? 1.f : 2.f) : fi;
            float4 v0, v1;
            v0.x = 0.25f * f0 * vals[0];
            v0.y = 0.25f * fi * vals[1];
            v0.z = 0.25f * fi * vals[2];
            v0.w = 0.25f * fi * vals[3];
            v1.x = 0.25f * fi * vals[4];
            v1.y = 0.25f * fi * vals[5];
            v1.z = 0.25f * fi * vals[6];
            v1.w = 0.25f * fi * vals[7];
            float4* dst = (float4*)(kout + i * 32 + 8 * jg);
            dst[0] = v0; dst[1] = v1;
        }
    }
}

// ---------------- P2: combined-direction kernel -> spectrum -------------------
__global__ __launch_bounds__(256) void build_gf(const float* __restrict__ k4,
                                                float2* __restrict__ Gf) {
    __shared__ float2 a[4096];
    int d = blockIdx.x, tid = threadIdx.x;
    int o = tid & 7;
    float2 tw[7];
#pragma unroll
    for (int k = 0; k < 7; ++k) {
        float s, co;
        sincosf(-TWO_PI * (float)(o * (k + 1)) / 64.f, &s, &co);
        tw[k] = make_float2(co, s);
    }
    for (int e = tid; e < 4096; e += 256) a[e] = make_float2(0.f, 0.f);
    __syncthreads();
#pragma unroll
    for (int k = 0; k < 4; ++k) {
        int cell = tid + 256 * k;
        int p = cell >> 5, q = cell & 31;
        float k0 = k4[(0 * 768 + d) * 1024 + cell];
        float k1 = k4[(1 * 768 + d) * 1024 + cell];
        float k2 = k4[(2 * 768 + d) * 1024 + cell];
        float k3 = k4[(3 * 768 + d) * 1024 + cell];
        int pn = (64 - p) & 63, qn = (64 - q) & 63;
        a[swz(p,  q )].x += k0;
        a[swz(pn, q )].x += k1;
        a[swz(p,  qn)].x += k2;
        a[swz(pn, qn)].x += k3;
    }
    __syncthreads();
#pragma unroll 1
    for (int sw = 0; sw < 2; ++sw) {          // rows 0..63, fwd
        int row = sw * 32 + (tid >> 3);
        float2 r[8];
#pragma unroll
        for (int j = 0; j < 8; ++j) r[j] = a[swz(row, 8 * j + o)];
        fft64<false, false, false>(a, r, tw, o, row);
#pragma unroll
        for (int m = 0; m < 8; ++m) a[swz(row, o + 8 * m)] = r[m];
    }
    __syncthreads();
#pragma unroll 1
    for (int sw = 0; sw < 2; ++sw) {          // cols 0..63, fwd; write natural
        int c = sw * 32 + (tid >> 3);
        float2 r[8];
#pragma unroll
        for (int j = 0; j < 8; ++j) r[j] = a[swz(8 * j + o, c)];
        fft64<false, true, false>(a, r, tw, o, c);
#pragma unroll
        for (int m = 0; m < 8; ++m) Gf[d * 4096 + (o + 8 * m) * 64 + c] = r[m];
    }
}

// ---------------- P3: FFT conv, two batch images packed re/im -----------------
__global__ __launch_bounds__(256) void conv_fft(
        const float* __restrict__ x, const float2* __restrict__ Gf,
        const float* __restrict__ omega, float* __restrict__ out,
        int directOut, float* __restrict__ outT) {
    __shared__ float2 a[4096];
    int bid = blockIdx.x;
    int d = bid >> 3, b = (bid & 7) * 2;
    int tid = threadIdx.x;
    int o = tid & 7;
    float2 tw[7];
#pragma unroll
    for (int k = 0; k < 7; ++k) {
        float s, co;
        sincosf(-TWO_PI * (float)(o * (k + 1)) / 64.f, &s, &co);
        tw[k] = make_float2(co, s);
    }
    // ---- forward rows (32 nonzero rows == 32 groups, one shot) ----
    {
        int row = tid >> 3;
        float2 r[8];
#pragma unroll
        for (int j = 0; j < 4; ++j) {
            int s2 = row * 32 + 8 * j + o;     // cols 8j+o < 32 always
            r[j] = make_float2(x[s2 * 12288 + b * 768 + d],
                               x[s2 * 12288 + (b + 1) * 768 + d]);
        }
#pragma unroll
        for (int j = 4; j < 8; ++j) r[j] = make_float2(0.f, 0.f);
        fft64<false, false, true>(a, r, tw, o, row);
#pragma unroll
        for (int m = 0; m < 8; ++m) a[swz(row, o + 8 * m)] = r[m];
    }
    __syncthreads();
    // ---- columns: fwd FFT ⊙ Gf, inv FFT — fully fused in registers ----
#pragma unroll 1
    for (int sw = 0; sw < 2; ++sw) {
        int c = sw * 32 + (tid >> 3);
        float2 r[8];
#pragma unroll
        for (int j = 0; j < 4; ++j) r[j] = a[swz(8 * j + o, c)];  // rows 8j+o < 32
#pragma unroll
        for (int j = 4; j < 8; ++j) r[j] = make_float2(0.f, 0.f);
        fft64<false, true, true>(a, r, tw, o, c);
#pragma unroll
        for (int m = 0; m < 8; ++m) {
            int u = o + 8 * m;
            r[m] = cmulf(r[m], Gf[d * 4096 + u * 64 + c]);
        }
        fft64<true, true, false>(a, r, tw, o, c);
#pragma unroll
        for (int m = 0; m < 4; ++m) a[swz(o + 8 * m, c)] = r[m];  // spatial rows <32
    }
    __syncthreads();
    // ---- inverse rows + epilogue ----
    {
        int row = tid >> 3;
        float2 r[8];
#pragma unroll
        for (int j = 0; j < 8; ++j) r[j] = a[swz(row, 8 * j + o)];
        fft64<true, false, false>(a, r, tw, o, row);
        float w = omega[d];
        const float inv = 1.0f / 4096.0f;
#pragma unroll
        for (int m = 0; m < 4; ++m) {
            int cc = o + 8 * m;                // spatial cols <32
            int s2 = row * 32 + cc;
            float xa = x[s2 * 12288 + b * 768 + d];
            float xb = x[s2 * 12288 + (b + 1) * 768 + d];
            float ya = r[m].x * inv + xa * w;
            float yb = r[m].y * inv + xb * w;
            float oa = ya / (1.0f + expf(-ya));
            float ob = yb / (1.0f + expf(-yb));
            if (directOut) {
                out[s2 * 12288 + b * 768 + d] = oa;
                out[s2 * 12288 + (b + 1) * 768 + d] = ob;
            } else {
                outT[(b * 768 + d) * 1024 + s2] = oa;
                outT[((b + 1) * 768 + d) * 1024 + s2] = ob;
            }
        }
    }
}

// ---------------- P4: (B*D, S) -> (S, B*D) transpose --------------------------
__global__ __launch_bounds__(256) void transpose_out(const float* __restrict__ outT,
                                                     float* __restrict__ out) {
    __shared__ float t[32][33];
    int bR = blockIdx.x % 384, bS = blockIdx.x / 384;
    int r0 = bR * 32, s0 = bS * 32;
    int tx = threadIdx.x & 31, ty = threadIdx.x >> 5;
#pragma unroll
    for (int k = 0; k < 4; ++k) {
        int r = ty + 8 * k;
        t[r][tx] = outT[(r0 + r) * 1024 + s0 + tx];
    }
    __syncthreads();
#pragma unroll
    for (int k = 0; k < 4; ++k) {
        int r = ty + 8 * k;
        out[(s0 + r) * 12288 + r0 + tx] = t[tx][r];
    }
}

extern "C" void kernel_launch(void* const* d_in, const int* in_sizes, int n_in,
                              void* d_out, int out_size, void* d_ws, size_t ws_size,
                              hipStream_t stream) {
    const float* x     = (const float*)d_in[0];
    const float* Aang  = (const float*)d_in[1];
    const float* Arad  = (const float*)d_in[2];
    const float* B1p   = (const float*)d_in[3];
    const float* B2p   = (const float*)d_in[4];
    const float* C1p   = (const float*)d_in[5];
    const float* C2p   = (const float*)d_in[6];
    const float* omega = (const float*)d_in[7];
    float* out = (float*)d_out;
    char* ws = (char*)d_ws;

    float*  k4   = (float*)ws;                              // 12,582,912 B
    float2* Gf   = (float2*)(ws + 12582912);                // 25,165,824 B
    float*  outT = (float*)(ws + 12582912 + 25165824);      // 50,331,648 B
    int direct = (ws_size < (size_t)88080384) ? 1 : 0;

    ssm_kernel<<<768, 256, 0, stream>>>(Aang, Arad, B1p, B2p, C1p, C2p, k4);
    build_gf<<<768, 256, 0, stream>>>(k4, Gf);
    conv_fft<<<6144, 256, 0, stream>>>(x, Gf, omega, out, direct, outT);
    if (!direct) transpose_out<<<12288, 256, 0, stream>>>(outT, out);
}

// Round 5
// 200.906 us; speedup vs baseline: 2.0798x; 1.2039x over previous
//
#include <hip/hip_runtime.h>
#include <cmath>

#define TWO_PI 6.283185307179586476925f

__device__ __forceinline__ float sigm(float v) { return 1.0f / (1.0f + expf(-v)); }
__device__ __forceinline__ float2 cadd(float2 a, float2 b) { return make_float2(a.x + b.x, a.y + b.y); }
__device__ __forceinline__ float2 csub(float2 a, float2 b) { return make_float2(a.x - b.x, a.y - b.y); }
__device__ __forceinline__ float2 cmulf(float2 a, float2 b) {
    return make_float2(a.x * b.x - a.y * b.y, a.x * b.y + a.y * b.x);
}

// XOR-swizzled cell address for the 64x64 float2 tile.
__device__ __forceinline__ int swz(int r, int c) {
    return (r << 6) | (c ^ ((r ^ (r << 3)) & 63));
}

// In-register 8-point DFT, natural-order outputs. INV = conj twiddles.
// HALF: inputs x[4..7] are known zero.
template<bool INV, bool HALF>
__device__ __forceinline__ void dft8(float2* x) {
    const float RS = 0.70710678118654752440f;
    float2 t0, t1, t2, t3, t4, t5, t6, t7;
    if (HALF) {
        t0 = x[0]; t4 = x[0]; t1 = x[1]; t5 = x[1];
        t2 = x[2]; t6 = x[2]; t3 = x[3]; t7 = x[3];
    } else {
        t0 = cadd(x[0], x[4]); t4 = csub(x[0], x[4]);
        t1 = cadd(x[1], x[5]); t5 = csub(x[1], x[5]);
        t2 = cadd(x[2], x[6]); t6 = csub(x[2], x[6]);
        t3 = cadd(x[3], x[7]); t7 = csub(x[3], x[7]);
    }
    float2 t5w, t6w, t7w;
    if (!INV) {
        t5w = make_float2(RS * (t5.x + t5.y), RS * (t5.y - t5.x));
        t6w = make_float2(t6.y, -t6.x);
        t7w = make_float2(RS * (t7.y - t7.x), -RS * (t7.x + t7.y));
    } else {
        t5w = make_float2(RS * (t5.x - t5.y), RS * (t5.y + t5.x));
        t6w = make_float2(-t6.y, t6.x);
        t7w = make_float2(-RS * (t7.x + t7.y), RS * (t7.x - t7.y));
    }
    float2 u0 = cadd(t0, t2), u2 = csub(t0, t2), u1 = cadd(t1, t3), dd = csub(t1, t3);
    float2 u3 = INV ? make_float2(-dd.y, dd.x) : make_float2(dd.y, -dd.x);
    x[0] = cadd(u0, u1); x[4] = csub(u0, u1); x[2] = cadd(u2, u3); x[6] = csub(u2, u3);
    float2 v0 = cadd(t4, t6w), v2 = csub(t4, t6w), v1 = cadd(t5w, t7w), ee = csub(t5w, t7w);
    float2 v3 = INV ? make_float2(-ee.y, ee.x) : make_float2(ee.y, -ee.x);
    x[1] = cadd(v0, v1); x[5] = csub(v0, v1); x[3] = cadd(v2, v3); x[7] = csub(v2, v3);
}

// 64-pt FFT over one line by an 8-lane group. Input: reg j = point (8j+o).
// Output: reg m = point (o+8m). Natural order; line's own cells as scratch.
template<bool INV, bool COL, bool HALF>
__device__ __forceinline__ void fft64(float2* a, float2* r, const float2* tw,
                                      int o, int line) {
    dft8<INV, HALF>(r);
#pragma unroll
    for (int k = 1; k < 8; ++k) {
        float2 w = tw[k - 1];
        if (INV) w.y = -w.y;
        r[k] = cmulf(r[k], w);
    }
#pragma unroll
    for (int m = 0; m < 8; ++m) {
        int s = 8 * o + m;
        a[COL ? swz(s, line) : swz(line, s)] = r[m];
    }
#pragma unroll
    for (int j = 0; j < 8; ++j) {
        int s = 8 * j + o;
        r[j] = a[COL ? swz(s, line) : swz(line, s)];
    }
    dft8<INV, false>(r);
}

// ---------------- P1: 2-D SSM impulse response --------------------------------
__global__ __launch_bounds__(256) void ssm_kernel(
        const float* __restrict__ Aang, const float* __restrict__ Arad,
        const float* __restrict__ B1p, const float* __restrict__ B2p,
        const float* __restrict__ C1p, const float* __restrict__ C2p,
        float* __restrict__ k4) {
    int c = (blockIdx.x << 2) + (threadIdx.x >> 6);
    int lane = threadIdx.x & 63;
    int jg = lane & 3;
    int n = lane >> 2;
    int gid = c * 16 + n;

    float ar[4], ai[4];
#pragma unroll
    for (int t = 0; t < 4; ++t) {
        float ang = sigm(Aang[t * 49152 + gid]) * TWO_PI;
        float rad = sigm(Arad[t * 49152 + gid]);
        float s, co;
        sincosf(ang, &s, &co);
        ar[t] = rad * co; ai[t] = rad * s;
    }
    float a1r = ar[0], a1i = ai[0], a2r = ar[1], a2i = ai[1];
    float a3r = ar[2], a3i = ai[2], a4r = ar[3], a4i = ai[3];
    float p2r = a1r * a1r - a1i * a1i, p2i = 2.f * a1r * a1i;
    float p4r = p2r * p2r - p2i * p2i, p4i = 2.f * p2r * p2i;
    float p8r = p4r * p4r - p4i * p4i, p8i = 2.f * p4r * p4i;

    const float2* B1v = (const float2*)B1p;
    const float2* B2v = (const float2*)B2p;
    const float2* C1v = (const float2*)C1p;
    const float2* C2v = (const float2*)C2p;
    float2 b1 = B1v[gid], b2 = B2v[gid], c1 = C1v[gid], c2 = C2v[gid];
    float b1r = sigm(b1.x), b1i = sigm(b1.y);
    float b2r = sigm(b2.x), b2i = sigm(b2.y);
    float c1r = c1.x, c1i = c1.y, c2r = c2.x, c2i = c2.y;

    float xhr[8], xhi[8], xvr[8], xvi[8];
#pragma unroll
    for (int m = 0; m < 8; ++m) { xhr[m] = 0.f; xhi[m] = 0.f; xvr[m] = 0.f; xvi[m] = 0.f; }

    float* kout = k4 + c * 1024;
    for (int i = 0; i < 32; ++i) {
#pragma unroll
        for (int m = 0; m < 8; ++m) {
            float nr = a3r * xhr[m] - a3i * xhi[m] + a4r * xvr[m] - a4i * xvi[m];
            float ni = a3r * xhi[m] + a3i * xhr[m] + a4r * xvi[m] + a4i * xvr[m];
            xvr[m] = nr; xvi[m] = ni;
        }
        if (i == 0 && jg == 0) { xvr[0] += b2r; xvi[0] += b2i; }

        float cr = 0.f, ci = 0.f;
#pragma unroll
        for (int m = 0; m < 8; ++m) {
            float t = a1r * cr - a1i * ci + a2r * xvr[m] - a2i * xvi[m];
            ci = a1r * ci + a1i * cr + a2r * xvi[m] + a2i * xvr[m];
            cr = t;
        }
        float Pr = p8r, Pi = p8i, Vr = cr, Vi = ci;
#pragma unroll
        for (int o = 1; o <= 2; o <<= 1) {
            int src = (jg >= o) ? (lane - o) : lane;
            float Pr2 = __shfl(Pr, src, 64);
            float Pi2 = __shfl(Pi, src, 64);
            float Vr2 = __shfl(Vr, src, 64);
            float Vi2 = __shfl(Vi, src, 64);
            if (jg >= o) {
                float nPr = Pr * Pr2 - Pi * Pi2;
                float nPi = Pr * Pi2 + Pi * Pr2;
                float nVr = Pr * Vr2 - Pi * Vi2 + Vr;
                float nVi = Pr * Vi2 + Pi * Vr2 + Vi;
                Pr = nPr; Pi = nPi; Vr = nVr; Vi = nVi;
            }
        }
        int srcp = (jg >= 1) ? (lane - 1) : lane;
        float Ppr = __shfl(Pr, srcp, 64);
        float Ppi = __shfl(Pi, srcp, 64);
        float Vpr = __shfl(Vr, srcp, 64);
        float Vpi = __shfl(Vi, srcp, 64);
        float h0r = (i == 0) ? b1r : 0.f, h0i = (i == 0) ? b1i : 0.f;
        float er, ei;
        if (jg == 0) { er = h0r; ei = h0i; }
        else {
            er = Ppr * h0r - Ppi * h0i + Vpr;
            ei = Ppr * h0i + Ppi * h0r + Vpi;
        }
        xhr[0] = er; xhi[0] = ei;
        float gr = er, gi = ei;
#pragma unroll
        for (int m = 1; m < 8; ++m) {
            float t = a1r * gr - a1i * gi + a2r * xvr[m - 1] - a2i * xvi[m - 1];
            gi = a1r * gi + a1i * gr + a2r * xvi[m - 1] + a2i * xvr[m - 1];
            gr = t; xhr[m] = gr; xhi[m] = gi;
        }
        float vals[8];
#pragma unroll
        for (int m = 0; m < 8; ++m) {
            float val = c1r * xhr[m] - c1i * xhi[m] + c2r * xvr[m] - c2i * xvi[m];
            val += __shfl_xor(val, 4, 64);
            val += __shfl_xor(val, 8, 64);
            val += __shfl_xor(val, 16, 64);
            val += __shfl_xor(val, 32, 64);
            vals[m] = val;
        }
        if (n == 0) {
            float fi = (i == 0) ? 2.f : 1.f;
            float f0 = (jg == 0) ? ((i == 0) ? 1.f : 2.f) : fi;
            float4 v0, v1;
            v0.x = 0.25f * f0 * vals[0];
            v0.y = 0.25f * fi * vals[1];
            v0.z = 0.25f * fi * vals[2];
            v0.w = 0.25f * fi * vals[3];
            v1.x = 0.25f * fi * vals[4];
            v1.y = 0.25f * fi * vals[5];
            v1.z = 0.25f * fi * vals[6];
            v1.w = 0.25f * fi * vals[7];
            float4* dst = (float4*)(kout + i * 32 + 8 * jg);
            dst[0] = v0; dst[1] = v1;
        }
    }
}

// ---------------- P2: combined-direction kernel -> spectrum -------------------
__global__ __launch_bounds__(256) void build_gf(const float* __restrict__ k4,
                                                float2* __restrict__ Gf) {
    __shared__ float2 a[4096];
    int d = blockIdx.x, tid = threadIdx.x;
    int o = tid & 7;
    float2 tw[7];
#pragma unroll
    for (int k = 0; k < 7; ++k) {
        float s, co;
        sincosf(-TWO_PI * (float)(o * (k + 1)) / 64.f, &s, &co);
        tw[k] = make_float2(co, s);
    }
    for (int e = tid; e < 4096; e += 256) a[e] = make_float2(0.f, 0.f);
    __syncthreads();
#pragma unroll
    for (int k = 0; k < 4; ++k) {
        int cell = tid + 256 * k;
        int p = cell >> 5, q = cell & 31;
        float k0 = k4[(0 * 768 + d) * 1024 + cell];
        float k1 = k4[(1 * 768 + d) * 1024 + cell];
        float k2 = k4[(2 * 768 + d) * 1024 + cell];
        float k3 = k4[(3 * 768 + d) * 1024 + cell];
        int pn = (64 - p) & 63, qn = (64 - q) & 63;
        a[swz(p,  q )].x += k0;
        a[swz(pn, q )].x += k1;
        a[swz(p,  qn)].x += k2;
        a[swz(pn, qn)].x += k3;
    }
    __syncthreads();
#pragma unroll 1
    for (int sw = 0; sw < 2; ++sw) {
        int row = sw * 32 + (tid >> 3);
        float2 r[8];
#pragma unroll
        for (int j = 0; j < 8; ++j) r[j] = a[swz(row, 8 * j + o)];
        fft64<false, false, false>(a, r, tw, o, row);
#pragma unroll
        for (int m = 0; m < 8; ++m) a[swz(row, o + 8 * m)] = r[m];
    }
    __syncthreads();
#pragma unroll 1
    for (int sw = 0; sw < 2; ++sw) {
        int c = sw * 32 + (tid >> 3);
        float2 r[8];
#pragma unroll
        for (int j = 0; j < 8; ++j) r[j] = a[swz(8 * j + o, c)];
        fft64<false, true, false>(a, r, tw, o, c);
#pragma unroll
        for (int m = 0; m < 8; ++m) Gf[d * 4096 + (o + 8 * m) * 64 + c] = r[m];
    }
}

// ---------------- P2b: x (S,BD) -> xT (BD,S) coalesced transpose --------------
__global__ __launch_bounds__(256) void transpose_in(const float* __restrict__ x,
                                                    float* __restrict__ xT) {
    __shared__ float t[32][33];
    int bR = blockIdx.x % 384, bS = blockIdx.x / 384;
    int r0 = bR * 32, s0 = bS * 32;
    int tx = threadIdx.x & 31, ty = threadIdx.x >> 5;
#pragma unroll
    for (int k = 0; k < 4; ++k) {
        int r = ty + 8 * k;
        t[r][tx] = x[(s0 + r) * 12288 + r0 + tx];
    }
    __syncthreads();
#pragma unroll
    for (int k = 0; k < 4; ++k) {
        int r = ty + 8 * k;
        xT[(r0 + r) * 1024 + s0 + tx] = t[tx][r];
    }
}

// ---------------- P3: FFT conv, two batch images packed re/im -----------------
// useT: read xT (row-major (b*768+d, s), coalesced) and write back into xT
// (alias; each row is owned exclusively by this block, read-before-write).
__global__ __launch_bounds__(256) void conv_fft(
        const float* __restrict__ x, float* __restrict__ xT,
        const float2* __restrict__ Gf, const float* __restrict__ omega,
        float* __restrict__ out, int useT) {
    __shared__ float2 a[4096];
    // XCD-chunked swizzle: 6144 = 8*768; same-d blocks (8 bpairs) colocate.
    int bid = (blockIdx.x & 7) * 768 + (blockIdx.x >> 3);
    int d = bid >> 3, b = (bid & 7) * 2;
    int tid = threadIdx.x;
    int o = tid & 7;
    float2 tw[7];
#pragma unroll
    for (int k = 0; k < 7; ++k) {
        float s, co;
        sincosf(-TWO_PI * (float)(o * (k + 1)) / 64.f, &s, &co);
        tw[k] = make_float2(co, s);
    }
    const size_t base0 = (size_t)(b * 768 + d) * 1024;
    const size_t base1 = (size_t)((b + 1) * 768 + d) * 1024;
    // ---- forward rows (32 nonzero rows == 32 groups, one shot) ----
    {
        int row = tid >> 3;
        float2 r[8];
#pragma unroll
        for (int j = 0; j < 4; ++j) {
            int s2 = row * 32 + 8 * j + o;
            if (useT) r[j] = make_float2(xT[base0 + s2], xT[base1 + s2]);
            else      r[j] = make_float2(x[s2 * 12288 + b * 768 + d],
                                         x[s2 * 12288 + (b + 1) * 768 + d]);
        }
#pragma unroll
        for (int j = 4; j < 8; ++j) r[j] = make_float2(0.f, 0.f);
        fft64<false, false, true>(a, r, tw, o, row);
#pragma unroll
        for (int m = 0; m < 8; ++m) a[swz(row, o + 8 * m)] = r[m];
    }
    __syncthreads();
    // ---- columns: fwd FFT ⊙ Gf, inv FFT — fused in registers ----
#pragma unroll 1
    for (int sw = 0; sw < 2; ++sw) {
        int c = sw * 32 + (tid >> 3);
        float2 r[8];
#pragma unroll
        for (int j = 0; j < 4; ++j) r[j] = a[swz(8 * j + o, c)];
#pragma unroll
        for (int j = 4; j < 8; ++j) r[j] = make_float2(0.f, 0.f);
        fft64<false, true, true>(a, r, tw, o, c);
#pragma unroll
        for (int m = 0; m < 8; ++m) {
            int u = o + 8 * m;
            r[m] = cmulf(r[m], Gf[d * 4096 + u * 64 + c]);
        }
        fft64<true, true, false>(a, r, tw, o, c);
#pragma unroll
        for (int m = 0; m < 4; ++m) a[swz(o + 8 * m, c)] = r[m];
    }
    __syncthreads();
    // ---- inverse rows + epilogue ----
    {
        int row = tid >> 3;
        float2 r[8];
#pragma unroll
        for (int j = 0; j < 8; ++j) r[j] = a[swz(row, 8 * j + o)];
        fft64<true, false, false>(a, r, tw, o, row);
        float w = omega[d];
        const float inv = 1.0f / 4096.0f;
#pragma unroll
        for (int m = 0; m < 4; ++m) {
            int cc = o + 8 * m;
            int s2 = row * 32 + cc;
            float xa, xb;
            if (useT) { xa = xT[base0 + s2]; xb = xT[base1 + s2]; }
            else {
                xa = x[s2 * 12288 + b * 768 + d];
                xb = x[s2 * 12288 + (b + 1) * 768 + d];
            }
            float ya = r[m].x * inv + xa * w;
            float yb = r[m].y * inv + xb * w;
            float oa = ya / (1.0f + expf(-ya));
            float ob = yb / (1.0f + expf(-yb));
            if (useT) {
                xT[base0 + s2] = oa;        // overwrite own row (outT alias)
                xT[base1 + s2] = ob;
            } else {
                out[s2 * 12288 + b * 768 + d] = oa;
                out[s2 * 12288 + (b + 1) * 768 + d] = ob;
            }
        }
    }
}

// ---------------- P4: (B*D, S) -> (S, B*D) transpose --------------------------
__global__ __launch_bounds__(256) void transpose_out(const float* __restrict__ outT,
                                                     float* __restrict__ out) {
    __shared__ float t[32][33];
    int bR = blockIdx.x % 384, bS = blockIdx.x / 384;
    int r0 = bR * 32, s0 = bS * 32;
    int tx = threadIdx.x & 31, ty = threadIdx.x >> 5;
#pragma unroll
    for (int k = 0; k < 4; ++k) {
        int r = ty + 8 * k;
        t[r][tx] = outT[(r0 + r) * 1024 + s0 + tx];
    }
    __syncthreads();
#pragma unroll
    for (int k = 0; k < 4; ++k) {
        int r = ty + 8 * k;
        out[(s0 + r) * 12288 + r0 + tx] = t[tx][r];
    }
}

extern "C" void kernel_launch(void* const* d_in, const int* in_sizes, int n_in,
                              void* d_out, int out_size, void* d_ws, size_t ws_size,
                              hipStream_t stream) {
    const float* x     = (const float*)d_in[0];
    const float* Aang  = (const float*)d_in[1];
    const float* Arad  = (const float*)d_in[2];
    const float* B1p   = (const float*)d_in[3];
    const float* B2p   = (const float*)d_in[4];
    const float* C1p   = (const float*)d_in[5];
    const float* C2p   = (const float*)d_in[6];
    const float* omega = (const float*)d_in[7];
    float* out = (float*)d_out;
    char* ws = (char*)d_ws;

    float*  k4 = (float*)ws;                                // 12,582,912 B
    float2* Gf = (float2*)(ws + 12582912);                  // 25,165,824 B
    float*  xT = (float*)(ws + 12582912 + 25165824);        // 50,331,648 B (in+out alias)
    int useT = (ws_size >= (size_t)88080384) ? 1 : 0;

    ssm_kernel<<<768, 256, 0, stream>>>(Aang, Arad, B1p, B2p, C1p, C2p, k4);
    build_gf<<<768, 256, 0, stream>>>(k4, Gf);
    if (useT) transpose_in<<<12288, 256, 0, stream>>>(x, xT);
    conv_fft<<<6144, 256, 0, stream>>>(x, xT, Gf, omega, out, useT);
    if (useT) transpose_out<<<12288, 256, 0, stream>>>(xT, out);
}

// Round 6
// 186.137 us; speedup vs baseline: 2.2448x; 1.0793x over previous
//
#include <hip/hip_runtime.h>
#include <cmath>

#define TWO_PI 6.283185307179586476925f

__device__ __forceinline__ float sigm(float v) { return 1.0f / (1.0f + expf(-v)); }
__device__ __forceinline__ float2 cadd(float2 a, float2 b) { return make_float2(a.x + b.x, a.y + b.y); }
__device__ __forceinline__ float2 csub(float2 a, float2 b) { return make_float2(a.x - b.x, a.y - b.y); }
__device__ __forceinline__ float2 cmulf(float2 a, float2 b) {
    return make_float2(a.x * b.x - a.y * b.y, a.x * b.y + a.y * b.x);
}

// XOR-swizzled cell address for the 64x64 float2 tile.
__device__ __forceinline__ int swz(int r, int c) {
    return (r << 6) | (c ^ ((r ^ (r << 3)) & 63));
}

// Gf layout: element (freq row u = o+8m, freq col c) at  o + 8*c + 512*m.
// Makes conv/gf spectrum accesses lane-contiguous (o fastest, then c).
__device__ __forceinline__ int gfidx(int o, int m, int c) {
    return o + (c << 3) + (m << 9);
}

// In-register 8-point DFT, natural-order outputs. INV = conj twiddles.
// HALF: inputs x[4..7] known zero.  PRUNE: skip outputs x[4..7].
template<bool INV, bool HALF, bool PRUNE>
__device__ __forceinline__ void dft8(float2* x) {
    const float RS = 0.70710678118654752440f;
    float2 t0, t1, t2, t3, t4, t5, t6, t7;
    if (HALF) {
        t0 = x[0]; t4 = x[0]; t1 = x[1]; t5 = x[1];
        t2 = x[2]; t6 = x[2]; t3 = x[3]; t7 = x[3];
    } else {
        t0 = cadd(x[0], x[4]); t4 = csub(x[0], x[4]);
        t1 = cadd(x[1], x[5]); t5 = csub(x[1], x[5]);
        t2 = cadd(x[2], x[6]); t6 = csub(x[2], x[6]);
        t3 = cadd(x[3], x[7]); t7 = csub(x[3], x[7]);
    }
    float2 t5w, t6w, t7w;
    if (!INV) {
        t5w = make_float2(RS * (t5.x + t5.y), RS * (t5.y - t5.x));
        t6w = make_float2(t6.y, -t6.x);
        t7w = make_float2(RS * (t7.y - t7.x), -RS * (t7.x + t7.y));
    } else {
        t5w = make_float2(RS * (t5.x - t5.y), RS * (t5.y + t5.x));
        t6w = make_float2(-t6.y, t6.x);
        t7w = make_float2(-RS * (t7.x + t7.y), RS * (t7.x - t7.y));
    }
    float2 u0 = cadd(t0, t2), u2 = csub(t0, t2), u1 = cadd(t1, t3), dd = csub(t1, t3);
    float2 u3 = INV ? make_float2(-dd.y, dd.x) : make_float2(dd.y, -dd.x);
    x[0] = cadd(u0, u1); x[2] = cadd(u2, u3);
    if (!PRUNE) { x[4] = csub(u0, u1); x[6] = csub(u2, u3); }
    float2 v0 = cadd(t4, t6w), v2 = csub(t4, t6w), v1 = cadd(t5w, t7w), ee = csub(t5w, t7w);
    float2 v3 = INV ? make_float2(-ee.y, ee.x) : make_float2(ee.y, -ee.x);
    x[1] = cadd(v0, v1); x[3] = cadd(v2, v3);
    if (!PRUNE) { x[5] = csub(v0, v1); x[7] = csub(v2, v3); }
}

__device__ __forceinline__ void make_tw(int o, float2* tw) {
    float s, co;
    sincosf(-TWO_PI * (float)o / 64.f, &s, &co);
    tw[0] = make_float2(co, s);
#pragma unroll
    for (int k = 1; k < 7; ++k) tw[k] = cmulf(tw[k - 1], tw[0]);
}

// 64-pt FFT over one line by an 8-lane group. In: reg j = point (8j+o).
// Out: reg m = point (o+8m) (PRUNE: only m<4 valid). Natural order.
template<bool INV, bool COL, bool HALF, bool PRUNE>
__device__ __forceinline__ void fft64(float2* a, float2* r, const float2* tw,
                                      int o, int line) {
    dft8<INV, HALF, false>(r);
#pragma unroll
    for (int k = 1; k < 8; ++k) {
        float2 w = tw[k - 1];
        if (INV) w.y = -w.y;
        r[k] = cmulf(r[k], w);
    }
#pragma unroll
    for (int m = 0; m < 8; ++m) {
        int s = 8 * o + m;
        a[COL ? swz(s, line) : swz(line, s)] = r[m];
    }
#pragma unroll
    for (int j = 0; j < 8; ++j) {
        int s = 8 * j + o;
        r[j] = a[COL ? swz(s, line) : swz(line, s)];
    }
    dft8<INV, false, PRUNE>(r);
}

// ---------------- P1: fused SSM impulse response + spectrum -------------------
// Block = channel d. Warp t = direction t (channel c = t*768+d).
// Per-direction k -> LDS kl[t]; deterministic gather with quadrant flips into
// the 64x64 tile; in-block 2D FFT; write Gf. No k4 global round-trip.
__global__ __launch_bounds__(256) void ssm_gf(
        const float* __restrict__ Aang, const float* __restrict__ Arad,
        const float* __restrict__ B1p, const float* __restrict__ B2p,
        const float* __restrict__ C1p, const float* __restrict__ C2p,
        float2* __restrict__ Gf) {
    __shared__ float2 a[4096];
    __shared__ float kl[4][32][36];
    int d = blockIdx.x;
    int tid = threadIdx.x;
    int t = tid >> 6;
    int lane = tid & 63;
    int jg = lane & 3;
    int n = lane >> 2;
    int c = t * 768 + d;
    int gid = c * 16 + n;

    float ar[4], ai[4];
#pragma unroll
    for (int q = 0; q < 4; ++q) {
        float ang = sigm(Aang[q * 49152 + gid]) * TWO_PI;
        float rad = sigm(Arad[q * 49152 + gid]);
        float s, co;
        sincosf(ang, &s, &co);
        ar[q] = rad * co; ai[q] = rad * s;
    }
    float a1r = ar[0], a1i = ai[0], a2r = ar[1], a2i = ai[1];
    float a3r = ar[2], a3i = ai[2], a4r = ar[3], a4i = ai[3];
    float p2r = a1r * a1r - a1i * a1i, p2i = 2.f * a1r * a1i;
    float p4r = p2r * p2r - p2i * p2i, p4i = 2.f * p2r * p2i;
    float p8r = p4r * p4r - p4i * p4i, p8i = 2.f * p4r * p4i;

    const float2* B1v = (const float2*)B1p;
    const float2* B2v = (const float2*)B2p;
    const float2* C1v = (const float2*)C1p;
    const float2* C2v = (const float2*)C2p;
    float2 b1 = B1v[gid], b2 = B2v[gid], c1 = C1v[gid], c2 = C2v[gid];
    float b1r = sigm(b1.x), b1i = sigm(b1.y);
    float b2r = sigm(b2.x), b2i = sigm(b2.y);
    float c1r = c1.x, c1i = c1.y, c2r = c2.x, c2i = c2.y;

    float xhr[8], xhi[8], xvr[8], xvi[8];
#pragma unroll
    for (int m = 0; m < 8; ++m) { xhr[m] = 0.f; xhi[m] = 0.f; xvr[m] = 0.f; xvi[m] = 0.f; }

    for (int i = 0; i < 32; ++i) {
#pragma unroll
        for (int m = 0; m < 8; ++m) {
            float nr = a3r * xhr[m] - a3i * xhi[m] + a4r * xvr[m] - a4i * xvi[m];
            float ni = a3r * xhi[m] + a3i * xhr[m] + a4r * xvi[m] + a4i * xvr[m];
            xvr[m] = nr; xvi[m] = ni;
        }
        if (i == 0 && jg == 0) { xvr[0] += b2r; xvi[0] += b2i; }

        float cr = 0.f, ci = 0.f;
#pragma unroll
        for (int m = 0; m < 8; ++m) {
            float tt = a1r * cr - a1i * ci + a2r * xvr[m] - a2i * xvi[m];
            ci = a1r * ci + a1i * cr + a2r * xvi[m] + a2i * xvr[m];
            cr = tt;
        }
        float Pr = p8r, Pi = p8i, Vr = cr, Vi = ci;
#pragma unroll
        for (int os = 1; os <= 2; os <<= 1) {
            int src = (jg >= os) ? (lane - os) : lane;
            float Pr2 = __shfl(Pr, src, 64);
            float Pi2 = __shfl(Pi, src, 64);
            float Vr2 = __shfl(Vr, src, 64);
            float Vi2 = __shfl(Vi, src, 64);
            if (jg >= os) {
                float nPr = Pr * Pr2 - Pi * Pi2;
                float nPi = Pr * Pi2 + Pi * Pr2;
                float nVr = Pr * Vr2 - Pi * Vi2 + Vr;
                float nVi = Pr * Vi2 + Pi * Vr2 + Vi;
                Pr = nPr; Pi = nPi; Vr = nVr; Vi = nVi;
            }
        }
        int srcp = (jg >= 1) ? (lane - 1) : lane;
        float Ppr = __shfl(Pr, srcp, 64);
        float Ppi = __shfl(Pi, srcp, 64);
        float Vpr = __shfl(Vr, srcp, 64);
        float Vpi = __shfl(Vi, srcp, 64);
        float h0r = (i == 0) ? b1r : 0.f, h0i = (i == 0) ? b1i : 0.f;
        float er, ei;
        if (jg == 0) { er = h0r; ei = h0i; }
        else {
            er = Ppr * h0r - Ppi * h0i + Vpr;
            ei = Ppr * h0i + Ppi * h0r + Vpi;
        }
        xhr[0] = er; xhi[0] = ei;
        float gr = er, gi = ei;
#pragma unroll
        for (int m = 1; m < 8; ++m) {
            float tt = a1r * gr - a1i * gi + a2r * xvr[m - 1] - a2i * xvi[m - 1];
            gi = a1r * gi + a1i * gr + a2r * xvi[m - 1] + a2i * xvr[m - 1];
            gr = tt; xhr[m] = gr; xhi[m] = gi;
        }
        float vals[8];
#pragma unroll
        for (int m = 0; m < 8; ++m) {
            float val = c1r * xhr[m] - c1i * xhi[m] + c2r * xvr[m] - c2i * xvi[m];
            val += __shfl_xor(val, 4, 64);
            val += __shfl_xor(val, 8, 64);
            val += __shfl_xor(val, 16, 64);
            val += __shfl_xor(val, 32, 64);
            vals[m] = val;
        }
        if (n == 0) {
            float fi = (i == 0) ? 2.f : 1.f;
            float f0 = (jg == 0) ? ((i == 0) ? 1.f : 2.f) : fi;
            float4 v0, v1;
            v0.x = 0.25f * f0 * vals[0];
            v0.y = 0.25f * fi * vals[1];
            v0.z = 0.25f * fi * vals[2];
            v0.w = 0.25f * fi * vals[3];
            v1.x = 0.25f * fi * vals[4];
            v1.y = 0.25f * fi * vals[5];
            v1.z = 0.25f * fi * vals[6];
            v1.w = 0.25f * fi * vals[7];
            float4* dst = (float4*)&kl[t][i][8 * jg];
            dst[0] = v0; dst[1] = v1;
        }
    }
    __syncthreads();
    // deterministic gather: combine the 4 flipped quadrants into the tile
    for (int e = tid; e < 4096; e += 256) {
        int r = e >> 6, cc = e & 63;
        int r2 = (64 - r) & 63, c2 = (64 - cc) & 63;
        float v = 0.f;
        if (r  < 32 && cc < 32) v += kl[0][r ][cc];
        if (r2 < 32 && cc < 32) v += kl[1][r2][cc];
        if (r  < 32 && c2 < 32) v += kl[2][r ][c2];
        if (r2 < 32 && c2 < 32) v += kl[3][r2][c2];
        a[swz(r, cc)] = make_float2(v, 0.f);
    }
    __syncthreads();
    // 2D forward FFT -> Gf
    int o = tid & 7;
    float2 tw[7];
    make_tw(o, tw);
#pragma unroll 1
    for (int sw = 0; sw < 2; ++sw) {
        int row = sw * 32 + (tid >> 3);
        float2 r[8];
#pragma unroll
        for (int j = 0; j < 8; ++j) r[j] = a[swz(row, 8 * j + o)];
        fft64<false, false, false, false>(a, r, tw, o, row);
#pragma unroll
        for (int m = 0; m < 8; ++m) a[swz(row, o + 8 * m)] = r[m];
    }
    __syncthreads();
#pragma unroll 1
    for (int sw = 0; sw < 2; ++sw) {
        int cc = sw * 32 + (tid >> 3);
        float2 r[8];
#pragma unroll
        for (int j = 0; j < 8; ++j) r[j] = a[swz(8 * j + o, cc)];
        fft64<false, true, false, false>(a, r, tw, o, cc);
#pragma unroll
        for (int m = 0; m < 8; ++m) Gf[d * 4096 + gfidx(o, m, cc)] = r[m];
    }
}

// ---------------- P2: x (S,BD) -> xT (BD,S), 64x64 tiles ----------------------
__global__ __launch_bounds__(256) void transpose_in(const float* __restrict__ x,
                                                    float* __restrict__ xT) {
    __shared__ float t[64][65];
    int bR = blockIdx.x % 192, bS = blockIdx.x / 192;
    int r0 = bR * 64, s0 = bS * 64;
    int c = threadIdx.x & 63, w = threadIdx.x >> 6;
#pragma unroll
    for (int k = 0; k < 16; ++k) {
        int row = w + 4 * k;
        t[row][c] = x[(size_t)(s0 + row) * 12288 + r0 + c];
    }
    __syncthreads();
#pragma unroll
    for (int k = 0; k < 16; ++k) {
        int row = w + 4 * k;
        xT[(size_t)(r0 + row) * 1024 + s0 + c] = t[c][row];
    }
}

// ---------------- P4: xT (BD,S) -> out (S,BD), 64x64 tiles --------------------
__global__ __launch_bounds__(256) void transpose_out(const float* __restrict__ xT,
                                                     float* __restrict__ out) {
    __shared__ float t[64][65];
    int bR = blockIdx.x % 192, bS = blockIdx.x / 192;
    int r0 = bR * 64, s0 = bS * 64;
    int c = threadIdx.x & 63, w = threadIdx.x >> 6;
#pragma unroll
    for (int k = 0; k < 16; ++k) {
        int row = w + 4 * k;
        t[row][c] = xT[(size_t)(r0 + row) * 1024 + s0 + c];
    }
    __syncthreads();
#pragma unroll
    for (int k = 0; k < 16; ++k) {
        int row = w + 4 * k;
        out[(size_t)(s0 + row) * 12288 + r0 + c] = t[c][row];
    }
}

// ---------------- P3: FFT conv, two batch images packed re/im -----------------
__global__ __launch_bounds__(256) void conv_fft(
        const float* __restrict__ x, float* __restrict__ xT,
        const float2* __restrict__ Gf, const float* __restrict__ omega,
        float* __restrict__ out, int useT) {
    __shared__ float2 a[4096];
    // XCD-chunked swizzle: same-d blocks (8 bpairs) colocate on one XCD.
    int bid = (blockIdx.x & 7) * 768 + (blockIdx.x >> 3);
    int d = bid >> 3, b = (bid & 7) * 2;
    int tid = threadIdx.x;
    int o = tid & 7;
    float2 tw[7];
    make_tw(o, tw);
    const size_t base0 = (size_t)(b * 768 + d) * 1024;
    const size_t base1 = (size_t)((b + 1) * 768 + d) * 1024;
    // ---- forward rows (32 nonzero rows == 32 groups, one shot) ----
    {
        int row = tid >> 3;
        float2 r[8];
#pragma unroll
        for (int j = 0; j < 4; ++j) {
            int s2 = row * 32 + 8 * j + o;
            if (useT) r[j] = make_float2(xT[base0 + s2], xT[base1 + s2]);
            else      r[j] = make_float2(x[s2 * 12288 + b * 768 + d],
                                         x[s2 * 12288 + (b + 1) * 768 + d]);
        }
#pragma unroll
        for (int j = 4; j < 8; ++j) r[j] = make_float2(0.f, 0.f);
        fft64<false, false, true, false>(a, r, tw, o, row);
#pragma unroll
        for (int m = 0; m < 8; ++m) a[swz(row, o + 8 * m)] = r[m];
    }
    __syncthreads();
    // ---- columns: fwd FFT ⊙ Gf, inv FFT — fused in registers ----
#pragma unroll 1
    for (int sw = 0; sw < 2; ++sw) {
        int c = sw * 32 + (tid >> 3);
        float2 r[8];
#pragma unroll
        for (int j = 0; j < 4; ++j) r[j] = a[swz(8 * j + o, c)];
#pragma unroll
        for (int j = 4; j < 8; ++j) r[j] = make_float2(0.f, 0.f);
        fft64<false, true, true, false>(a, r, tw, o, c);
#pragma unroll
        for (int m = 0; m < 8; ++m) {
            r[m] = cmulf(r[m], Gf[d * 4096 + gfidx(o, m, c)]);
        }
        fft64<true, true, false, true>(a, r, tw, o, c);
#pragma unroll
        for (int m = 0; m < 4; ++m) a[swz(o + 8 * m, c)] = r[m];
    }
    __syncthreads();
    // ---- inverse rows + epilogue ----
    {
        int row = tid >> 3;
        float2 r[8];
#pragma unroll
        for (int j = 0; j < 8; ++j) r[j] = a[swz(row, 8 * j + o)];
        fft64<true, false, false, true>(a, r, tw, o, row);
        float w = omega[d];
        const float inv = 1.0f / 4096.0f;
#pragma unroll
        for (int m = 0; m < 4; ++m) {
            int cc = o + 8 * m;
            int s2 = row * 32 + cc;
            float xa, xb;
            if (useT) { xa = xT[base0 + s2]; xb = xT[base1 + s2]; }
            else {
                xa = x[s2 * 12288 + b * 768 + d];
                xb = x[s2 * 12288 + (b + 1) * 768 + d];
            }
            float ya = r[m].x * inv + xa * w;
            float yb = r[m].y * inv + xb * w;
            float oa = ya / (1.0f + expf(-ya));
            float ob = yb / (1.0f + expf(-yb));
            if (useT) {
                xT[base0 + s2] = oa;        // overwrite own row (outT alias)
                xT[base1 + s2] = ob;
            } else {
                out[s2 * 12288 + b * 768 + d] = oa;
                out[s2 * 12288 + (b + 1) * 768 + d] = ob;
            }
        }
    }
}

extern "C" void kernel_launch(void* const* d_in, const int* in_sizes, int n_in,
                              void* d_out, int out_size, void* d_ws, size_t ws_size,
                              hipStream_t stream) {
    const float* x     = (const float*)d_in[0];
    const float* Aang  = (const float*)d_in[1];
    const float* Arad  = (const float*)d_in[2];
    const float* B1p   = (const float*)d_in[3];
    const float* B2p   = (const float*)d_in[4];
    const float* C1p   = (const float*)d_in[5];
    const float* C2p   = (const float*)d_in[6];
    const float* omega = (const float*)d_in[7];
    float* out = (float*)d_out;
    char* ws = (char*)d_ws;

    float2* Gf = (float2*)ws;                       // 25,165,824 B
    float*  xT = (float*)(ws + 25165824);           // 50,331,648 B (in+out alias)
    int useT = (ws_size >= (size_t)75497472) ? 1 : 0;

    ssm_gf<<<768, 256, 0, stream>>>(Aang, Arad, B1p, B2p, C1p, C2p, Gf);
    if (useT) transpose_in<<<3072, 256, 0, stream>>>(x, xT);
    conv_fft<<<6144, 256, 0, stream>>>(x, xT, Gf, omega, out, useT);
    if (useT) transpose_out<<<3072, 256, 0, stream>>>(xT, out);
}

// Round 7
// 176.791 us; speedup vs baseline: 2.3635x; 1.0529x over previous
//
#include <hip/hip_runtime.h>
#include <cmath>

#define TWO_PI 6.283185307179586476925f

__device__ __forceinline__ float sigm(float v) { return 1.0f / (1.0f + expf(-v)); }
__device__ __forceinline__ float2 cadd(float2 a, float2 b) { return make_float2(a.x + b.x, a.y + b.y); }
__device__ __forceinline__ float2 csub(float2 a, float2 b) { return make_float2(a.x - b.x, a.y - b.y); }
__device__ __forceinline__ float2 cmulf(float2 a, float2 b) {
    return make_float2(a.x * b.x - a.y * b.y, a.x * b.y + a.y * b.x);
}

// XOR-swizzled cell address for the 64x64 float2 tile.
__device__ __forceinline__ int swz(int r, int c) {
    return (r << 6) | (c ^ ((r ^ (r << 3)) & 63));
}

// Gf layout: element (freq row u = o+8m, freq col c) at  o + 8*c + 512*m.
__device__ __forceinline__ int gfidx(int o, int m, int c) {
    return o + (c << 3) + (m << 9);
}

// In-register 8-point DFT. INV: conj twiddles. HALF: x[4..7] zero. PRUNE: skip x[4..7] outs.
template<bool INV, bool HALF, bool PRUNE>
__device__ __forceinline__ void dft8(float2* x) {
    const float RS = 0.70710678118654752440f;
    float2 t0, t1, t2, t3, t4, t5, t6, t7;
    if (HALF) {
        t0 = x[0]; t4 = x[0]; t1 = x[1]; t5 = x[1];
        t2 = x[2]; t6 = x[2]; t3 = x[3]; t7 = x[3];
    } else {
        t0 = cadd(x[0], x[4]); t4 = csub(x[0], x[4]);
        t1 = cadd(x[1], x[5]); t5 = csub(x[1], x[5]);
        t2 = cadd(x[2], x[6]); t6 = csub(x[2], x[6]);
        t3 = cadd(x[3], x[7]); t7 = csub(x[3], x[7]);
    }
    float2 t5w, t6w, t7w;
    if (!INV) {
        t5w = make_float2(RS * (t5.x + t5.y), RS * (t5.y - t5.x));
        t6w = make_float2(t6.y, -t6.x);
        t7w = make_float2(RS * (t7.y - t7.x), -RS * (t7.x + t7.y));
    } else {
        t5w = make_float2(RS * (t5.x - t5.y), RS * (t5.y + t5.x));
        t6w = make_float2(-t6.y, t6.x);
        t7w = make_float2(-RS * (t7.x + t7.y), RS * (t7.x - t7.y));
    }
    float2 u0 = cadd(t0, t2), u2 = csub(t0, t2), u1 = cadd(t1, t3), dd = csub(t1, t3);
    float2 u3 = INV ? make_float2(-dd.y, dd.x) : make_float2(dd.y, -dd.x);
    x[0] = cadd(u0, u1); x[2] = cadd(u2, u3);
    if (!PRUNE) { x[4] = csub(u0, u1); x[6] = csub(u2, u3); }
    float2 v0 = cadd(t4, t6w), v2 = csub(t4, t6w), v1 = cadd(t5w, t7w), ee = csub(t5w, t7w);
    float2 v3 = INV ? make_float2(-ee.y, ee.x) : make_float2(ee.y, -ee.x);
    x[1] = cadd(v0, v1); x[3] = cadd(v2, v3);
    if (!PRUNE) { x[5] = csub(v0, v1); x[7] = csub(v2, v3); }
}

__device__ __forceinline__ void make_tw(int o, float2* tw) {
    float s, co;
    sincosf(-TWO_PI * (float)o / 64.f, &s, &co);
    tw[0] = make_float2(co, s);
#pragma unroll
    for (int k = 1; k < 7; ++k) tw[k] = cmulf(tw[k - 1], tw[0]);
}

// 64-pt FFT over one line by an 8-lane group. In: reg j = point (8j+o).
// Out: reg m = point (o+8m) (PRUNE: only m<4 valid). Natural order.
template<bool INV, bool COL, bool HALF, bool PRUNE>
__device__ __forceinline__ void fft64(float2* a, float2* r, const float2* tw,
                                      int o, int line) {
    dft8<INV, HALF, false>(r);
#pragma unroll
    for (int k = 1; k < 8; ++k) {
        float2 w = tw[k - 1];
        if (INV) w.y = -w.y;
        r[k] = cmulf(r[k], w);
    }
#pragma unroll
    for (int m = 0; m < 8; ++m) {
        int s = 8 * o + m;
        a[COL ? swz(s, line) : swz(line, s)] = r[m];
    }
#pragma unroll
    for (int j = 0; j < 8; ++j) {
        int s = 8 * j + o;
        r[j] = a[COL ? swz(s, line) : swz(line, s)];
    }
    dft8<INV, false, PRUNE>(r);
}

// ---------------- P1: fused SSM impulse response + spectrum -------------------
// Block = channel d, 512 thr = 8 warps = 4 dirs x 2 n-halves.
// lane = jg(0..7, 4 cols each) + 8*n8 (state dims n = n8 + 8*nh).
// Horizontal scan: 8-group Kogge-Stone of (A1^4, d) linear maps.
// Writes go straight into the 64x64 tile with quadrant flips; n-halves use
// the .x/.y components; dir overlaps (row-0/col-0 sources) use LDS atomicAdd.
__global__ __launch_bounds__(512) void ssm_gf(
        const float* __restrict__ Aang, const float* __restrict__ Arad,
        const float* __restrict__ B1p, const float* __restrict__ B2p,
        const float* __restrict__ C1p, const float* __restrict__ C2p,
        float2* __restrict__ Gf) {
    __shared__ float2 a[4096];
    int d = blockIdx.x;
    int tid = threadIdx.x;
    int w = tid >> 6;
    int t = w & 3;
    int nh = w >> 2;
    int lane = tid & 63;
    int jg = lane & 7;
    int n8 = lane >> 3;
    int n = n8 + 8 * nh;
    int c = t * 768 + d;
    int gid = c * 16 + n;

    for (int e = tid; e < 4096; e += 512) a[e] = make_float2(0.f, 0.f);

    float ar[4], ai[4];
#pragma unroll
    for (int q = 0; q < 4; ++q) {
        float ang = sigm(Aang[q * 49152 + gid]) * TWO_PI;
        float rad = sigm(Arad[q * 49152 + gid]);
        float s, co;
        sincosf(ang, &s, &co);
        ar[q] = rad * co; ai[q] = rad * s;
    }
    float a1r = ar[0], a1i = ai[0], a2r = ar[1], a2i = ai[1];
    float a3r = ar[2], a3i = ai[2], a4r = ar[3], a4i = ai[3];
    float p2r = a1r * a1r - a1i * a1i, p2i = 2.f * a1r * a1i;       // A1^2
    float p4r = p2r * p2r - p2i * p2i, p4i = 2.f * p2r * p2i;       // A1^4
    float pw3r = a1r * p2r - a1i * p2i, pw3i = a1r * p2i + a1i * p2r; // A1^3

    const float2* B1v = (const float2*)B1p;
    const float2* B2v = (const float2*)B2p;
    const float2* C1v = (const float2*)C1p;
    const float2* C2v = (const float2*)C2p;
    float2 b1 = B1v[gid], b2 = B2v[gid], c1 = C1v[gid], c2 = C2v[gid];
    float b1r = sigm(b1.x), b1i = sigm(b1.y);
    float b2r = sigm(b2.x), b2i = sigm(b2.y);
    float c1r = c1.x, c1i = c1.y, c2r = c2.x, c2i = c2.y;

    __syncthreads();

    float xvr[4], xvi[4], xhr[4], xhi[4];
#pragma unroll
    for (int m = 0; m < 4; ++m) { xvr[m] = 0.f; xvi[m] = 0.f; xhr[m] = 0.f; xhi[m] = 0.f; }

    for (int i = 0; i < 32; ++i) {
        // vertical: xv = A3*xh_prev + A4*xv_prev (+ B2 impulse at (0,0))
#pragma unroll
        for (int m = 0; m < 4; ++m) {
            float nr = a3r * xhr[m] - a3i * xhi[m] + a4r * xvr[m] - a4i * xvi[m];
            float ni = a3r * xhi[m] + a3i * xhr[m] + a4r * xvi[m] + a4i * xvr[m];
            xvr[m] = nr; xvi[m] = ni;
        }
        if (i == 0 && jg == 0) { xvr[0] += b2r; xvi[0] += b2i; }

        // zero-entry chain g0[m] and segment load d = A1*g0[3] + A2*xv[3]
        float g1r = a2r * xvr[0] - a2i * xvi[0];
        float g1i = a2r * xvi[0] + a2i * xvr[0];
        float g2r = a1r * g1r - a1i * g1i + a2r * xvr[1] - a2i * xvi[1];
        float g2i = a1r * g1i + a1i * g1r + a2r * xvi[1] + a2i * xvr[1];
        float g3r = a1r * g2r - a1i * g2i + a2r * xvr[2] - a2i * xvi[2];
        float g3i = a1r * g2i + a1i * g2r + a2r * xvi[2] + a2i * xvr[2];
        float ldr = a1r * g3r - a1i * g3i + a2r * xvr[3] - a2i * xvi[3];
        float ldi = a1r * g3i + a1i * g3r + a2r * xvi[3] + a2i * xvr[3];

        // 8-group Kogge-Stone inclusive scan of f(e) = A1^4*e + ld
        float Pr = p4r, Pi = p4i, Vr = ldr, Vi = ldi;
#pragma unroll
        for (int os = 1; os <= 4; os <<= 1) {
            int src = (jg >= os) ? (lane - os) : lane;
            float Pr2 = __shfl(Pr, src, 64);
            float Pi2 = __shfl(Pi, src, 64);
            float Vr2 = __shfl(Vr, src, 64);
            float Vi2 = __shfl(Vi, src, 64);
            if (jg >= os) {
                float nPr = Pr * Pr2 - Pi * Pi2;
                float nPi = Pr * Pi2 + Pi * Pr2;
                float nVr = Pr * Vr2 - Pi * Vi2 + Vr;
                float nVi = Pr * Vi2 + Pi * Vr2 + Vi;
                Pr = nPr; Pi = nPi; Vr = nVr; Vi = nVi;
            }
        }
        int srcp = (jg >= 1) ? (lane - 1) : lane;
        float Ppr = __shfl(Pr, srcp, 64);
        float Ppi = __shfl(Pi, srcp, 64);
        float Vpr = __shfl(Vr, srcp, 64);
        float Vpi = __shfl(Vi, srcp, 64);
        float er, ei;
        if (jg == 0) {
            er = (i == 0) ? b1r : 0.f; ei = (i == 0) ? b1i : 0.f;
        } else if (i == 0) {
            er = Ppr * b1r - Ppi * b1i + Vpr;
            ei = Ppr * b1i + Ppi * b1r + Vpi;
        } else {
            er = Vpr; ei = Vpi;
        }
        // xh[m] = A1^m * e + g0[m]  (ILP, no serial fill)
        xhr[0] = er; xhi[0] = ei;
        xhr[1] = a1r * er - a1i * ei + g1r;  xhi[1] = a1r * ei + a1i * er + g1i;
        xhr[2] = p2r * er - p2i * ei + g2r;  xhi[2] = p2r * ei + p2i * er + g2i;
        xhr[3] = pw3r * er - pw3i * ei + g3r; xhi[3] = pw3r * ei + pw3i * er + g3i;

        // C-dot per column
        float v0 = c1r * xhr[0] - c1i * xhi[0] + c2r * xvr[0] - c2i * xvi[0];
        float v1 = c1r * xhr[1] - c1i * xhi[1] + c2r * xvr[1] - c2i * xvi[1];
        float v2 = c1r * xhr[2] - c1i * xhi[2] + c2r * xvr[2] - c2i * xvi[2];
        float v3 = c1r * xhr[3] - c1i * xhi[3] + c2r * xvr[3] - c2i * xvi[3];

        // multi-value butterfly reduce over n8 (3 shuffles for 4 values)
        int bb0 = n8 & 1, bb1 = (n8 >> 1) & 1;
        float s0 = bb0 ? v0 : v2;
        float s1 = bb0 ? v1 : v3;
        float r0 = __shfl_xor(s0, 8, 64);
        float r1 = __shfl_xor(s1, 8, 64);
        float q0 = (bb0 ? v2 : v0) + r0;
        float q1 = (bb0 ? v3 : v1) + r1;
        float s2 = bb1 ? q0 : q1;
        float r2 = __shfl_xor(s2, 16, 64);
        float qq = (bb1 ? q1 : q0) + r2;
        qq += __shfl_xor(qq, 32, 64);
        // lane (jg, n8) holds S[idx], idx = 2*bb0 + bb1, summed over this warp's 8 n's
        if (n8 < 4) {
            int idx = 2 * bb0 + bb1;
            int col = 4 * jg + idx;
            float f = 0.25f;
            if (i == 0) f *= 2.f;
            if (col == 0) f *= 2.f;
            if (i == 0 && col == 0) f *= 0.25f;
            float val = f * qq;
            int rr_ = (t & 1) ? ((64 - i) & 63) : i;
            int cc_ = (t & 2) ? ((64 - col) & 63) : col;
            float* dst = ((float*)&a[swz(rr_, cc_)]) + nh;
            if (i == 0 || col == 0) atomicAdd(dst, val);   // dir-overlap edges
            else *dst = val;                               // bijective interior
        }
    }
    __syncthreads();
    // fold the two n-half components
    for (int e = tid; e < 4096; e += 512) {
        float2 cv = a[e];
        a[e] = make_float2(cv.x + cv.y, 0.f);
    }
    __syncthreads();
    // 2D forward FFT -> Gf (single sweeps, 64 groups)
    int o = tid & 7;
    float2 tw[7];
    make_tw(o, tw);
    {
        int row = tid >> 3;
        float2 r[8];
#pragma unroll
        for (int j = 0; j < 8; ++j) r[j] = a[swz(row, 8 * j + o)];
        fft64<false, false, false, false>(a, r, tw, o, row);
#pragma unroll
        for (int m = 0; m < 8; ++m) a[swz(row, o + 8 * m)] = r[m];
    }
    __syncthreads();
    {
        int cc = tid >> 3;
        float2 r[8];
#pragma unroll
        for (int j = 0; j < 8; ++j) r[j] = a[swz(8 * j + o, cc)];
        fft64<false, true, false, false>(a, r, tw, o, cc);
#pragma unroll
        for (int m = 0; m < 8; ++m) Gf[d * 4096 + gfidx(o, m, cc)] = r[m];
    }
}

// ---------------- P2: x (S,BD) -> xT (BD,S), 64x64 tiles ----------------------
__global__ __launch_bounds__(256) void transpose_in(const float* __restrict__ x,
                                                    float* __restrict__ xT) {
    __shared__ float t[64][65];
    int bR = blockIdx.x % 192, bS = blockIdx.x / 192;
    int r0 = bR * 64, s0 = bS * 64;
    int c = threadIdx.x & 63, w = threadIdx.x >> 6;
#pragma unroll
    for (int k = 0; k < 16; ++k) {
        int row = w + 4 * k;
        t[row][c] = x[(size_t)(s0 + row) * 12288 + r0 + c];
    }
    __syncthreads();
#pragma unroll
    for (int k = 0; k < 16; ++k) {
        int row = w + 4 * k;
        xT[(size_t)(r0 + row) * 1024 + s0 + c] = t[c][row];
    }
}

// ---------------- P4: xT (BD,S) -> out (S,BD), 64x64 tiles --------------------
__global__ __launch_bounds__(256) void transpose_out(const float* __restrict__ xT,
                                                     float* __restrict__ out) {
    __shared__ float t[64][65];
    int bR = blockIdx.x % 192, bS = blockIdx.x / 192;
    int r0 = bR * 64, s0 = bS * 64;
    int c = threadIdx.x & 63, w = threadIdx.x >> 6;
#pragma unroll
    for (int k = 0; k < 16; ++k) {
        int row = w + 4 * k;
        t[row][c] = xT[(size_t)(r0 + row) * 1024 + s0 + c];
    }
    __syncthreads();
#pragma unroll
    for (int k = 0; k < 16; ++k) {
        int row = w + 4 * k;
        out[(size_t)(s0 + row) * 12288 + r0 + c] = t[c][row];
    }
}

// ---------------- P3: FFT conv, two batch images packed re/im -----------------
__global__ __launch_bounds__(256) void conv_fft(
        const float* __restrict__ x, float* __restrict__ xT,
        const float2* __restrict__ Gf, const float* __restrict__ omega,
        float* __restrict__ out, int useT) {
    __shared__ float2 a[4096];
    // XCD-chunked swizzle: same-d blocks (8 bpairs) colocate on one XCD.
    int bid = (blockIdx.x & 7) * 768 + (blockIdx.x >> 3);
    int d = bid >> 3, b = (bid & 7) * 2;
    int tid = threadIdx.x;
    int o = tid & 7;
    float2 tw[7];
    make_tw(o, tw);
    const size_t base0 = (size_t)(b * 768 + d) * 1024;
    const size_t base1 = (size_t)((b + 1) * 768 + d) * 1024;
    // ---- forward rows (32 nonzero rows == 32 groups, one shot) ----
    {
        int row = tid >> 3;
        float2 r[8];
#pragma unroll
        for (int j = 0; j < 4; ++j) {
            int s2 = row * 32 + 8 * j + o;
            if (useT) r[j] = make_float2(xT[base0 + s2], xT[base1 + s2]);
            else      r[j] = make_float2(x[s2 * 12288 + b * 768 + d],
                                         x[s2 * 12288 + (b + 1) * 768 + d]);
        }
#pragma unroll
        for (int j = 4; j < 8; ++j) r[j] = make_float2(0.f, 0.f);
        fft64<false, false, true, false>(a, r, tw, o, row);
#pragma unroll
        for (int m = 0; m < 8; ++m) a[swz(row, o + 8 * m)] = r[m];
    }
    __syncthreads();
    // ---- columns: fwd FFT ⊙ Gf, inv FFT — fused in registers ----
#pragma unroll 1
    for (int sw = 0; sw < 2; ++sw) {
        int c = sw * 32 + (tid >> 3);
        float2 r[8];
#pragma unroll
        for (int j = 0; j < 4; ++j) r[j] = a[swz(8 * j + o, c)];
#pragma unroll
        for (int j = 4; j < 8; ++j) r[j] = make_float2(0.f, 0.f);
        fft64<false, true, true, false>(a, r, tw, o, c);
#pragma unroll
        for (int m = 0; m < 8; ++m) {
            r[m] = cmulf(r[m], Gf[d * 4096 + gfidx(o, m, c)]);
        }
        fft64<true, true, false, true>(a, r, tw, o, c);
#pragma unroll
        for (int m = 0; m < 4; ++m) a[swz(o + 8 * m, c)] = r[m];
    }
    __syncthreads();
    // ---- inverse rows + epilogue ----
    {
        int row = tid >> 3;
        float2 r[8];
#pragma unroll
        for (int j = 0; j < 8; ++j) r[j] = a[swz(row, 8 * j + o)];
        fft64<true, false, false, true>(a, r, tw, o, row);
        float w = omega[d];
        const float inv = 1.0f / 4096.0f;
#pragma unroll
        for (int m = 0; m < 4; ++m) {
            int cc = o + 8 * m;
            int s2 = row * 32 + cc;
            float xa, xb;
            if (useT) { xa = xT[base0 + s2]; xb = xT[base1 + s2]; }
            else {
                xa = x[s2 * 12288 + b * 768 + d];
                xb = x[s2 * 12288 + (b + 1) * 768 + d];
            }
            float ya = r[m].x * inv + xa * w;
            float yb = r[m].y * inv + xb * w;
            float oa = ya / (1.0f + expf(-ya));
            float ob = yb / (1.0f + expf(-yb));
            if (useT) {
                xT[base0 + s2] = oa;        // overwrite own row (outT alias)
                xT[base1 + s2] = ob;
            } else {
                out[s2 * 12288 + b * 768 + d] = oa;
                out[s2 * 12288 + (b + 1) * 768 + d] = ob;
            }
        }
    }
}

extern "C" void kernel_launch(void* const* d_in, const int* in_sizes, int n_in,
                              void* d_out, int out_size, void* d_ws, size_t ws_size,
                              hipStream_t stream) {
    const float* x     = (const float*)d_in[0];
    const float* Aang  = (const float*)d_in[1];
    const float* Arad  = (const float*)d_in[2];
    const float* B1p   = (const float*)d_in[3];
    const float* B2p   = (const float*)d_in[4];
    const float* C1p   = (const float*)d_in[5];
    const float* C2p   = (const float*)d_in[6];
    const float* omega = (const float*)d_in[7];
    float* out = (float*)d_out;
    char* ws = (char*)d_ws;

    float2* Gf = (float2*)ws;                       // 25,165,824 B
    float*  xT = (float*)(ws + 25165824);           // 50,331,648 B (in+out alias)
    int useT = (ws_size >= (size_t)75497472) ? 1 : 0;

    ssm_gf<<<768, 512, 0, stream>>>(Aang, Arad, B1p, B2p, C1p, C2p, Gf);
    if (useT) transpose_in<<<3072, 256, 0, stream>>>(x, xT);
    conv_fft<<<6144, 256, 0, stream>>>(x, xT, Gf, omega, out, useT);
    if (useT) transpose_out<<<3072, 256, 0, stream>>>(xT, out);
}

// Round 8
// 168.264 us; speedup vs baseline: 2.4833x; 1.0507x over previous
//
#include <hip/hip_runtime.h>
#include <cmath>

#define TWO_PI 6.283185307179586476925f

__device__ __forceinline__ float sigm(float v) { return 1.0f / (1.0f + expf(-v)); }
__device__ __forceinline__ float2 cadd(float2 a, float2 b) { return make_float2(a.x + b.x, a.y + b.y); }
__device__ __forceinline__ float2 csub(float2 a, float2 b) { return make_float2(a.x - b.x, a.y - b.y); }
__device__ __forceinline__ float2 cmulf(float2 a, float2 b) {
    return make_float2(a.x * b.x - a.y * b.y, a.x * b.y + a.y * b.x);
}

// DPP lane move within 16-lane rows; invalid sources read 0 (bound_ctrl).
template<int CTRL>
__device__ __forceinline__ float dpp0(float v) {
    return __int_as_float(__builtin_amdgcn_update_dpp(
        0, __float_as_int(v), CTRL, 0xf, 0xf, true));
}
#define DPP_SHR1 0x111
#define DPP_SHR2 0x112
#define DPP_SHR4 0x114
#define DPP_ROR8 0x128

__device__ __forceinline__ float swz_xor16(float v) {
    return __int_as_float(__builtin_amdgcn_ds_swizzle(__float_as_int(v), 0x401F));
}

// XOR-swizzled cell address for the 64x64 float2 tile.
__device__ __forceinline__ int swz(int r, int c) {
    return (r << 6) | (c ^ ((r ^ (r << 3)) & 63));
}

// Gf layout: element (freq row u = o+8m, freq col c) at  o + 8*c + 512*m.
__device__ __forceinline__ int gfidx(int o, int m, int c) {
    return o + (c << 3) + (m << 9);
}

// In-register 8-point DFT. INV: conj twiddles. HALF: x[4..7] zero. PRUNE: skip x[4..7] outs.
template<bool INV, bool HALF, bool PRUNE>
__device__ __forceinline__ void dft8(float2* x) {
    const float RS = 0.70710678118654752440f;
    float2 t0, t1, t2, t3, t4, t5, t6, t7;
    if (HALF) {
        t0 = x[0]; t4 = x[0]; t1 = x[1]; t5 = x[1];
        t2 = x[2]; t6 = x[2]; t3 = x[3]; t7 = x[3];
    } else {
        t0 = cadd(x[0], x[4]); t4 = csub(x[0], x[4]);
        t1 = cadd(x[1], x[5]); t5 = csub(x[1], x[5]);
        t2 = cadd(x[2], x[6]); t6 = csub(x[2], x[6]);
        t3 = cadd(x[3], x[7]); t7 = csub(x[3], x[7]);
    }
    float2 t5w, t6w, t7w;
    if (!INV) {
        t5w = make_float2(RS * (t5.x + t5.y), RS * (t5.y - t5.x));
        t6w = make_float2(t6.y, -t6.x);
        t7w = make_float2(RS * (t7.y - t7.x), -RS * (t7.x + t7.y));
    } else {
        t5w = make_float2(RS * (t5.x - t5.y), RS * (t5.y + t5.x));
        t6w = make_float2(-t6.y, t6.x);
        t7w = make_float2(-RS * (t7.x + t7.y), RS * (t7.x - t7.y));
    }
    float2 u0 = cadd(t0, t2), u2 = csub(t0, t2), u1 = cadd(t1, t3), dd = csub(t1, t3);
    float2 u3 = INV ? make_float2(-dd.y, dd.x) : make_float2(dd.y, -dd.x);
    x[0] = cadd(u0, u1); x[2] = cadd(u2, u3);
    if (!PRUNE) { x[4] = csub(u0, u1); x[6] = csub(u2, u3); }
    float2 v0 = cadd(t4, t6w), v2 = csub(t4, t6w), v1 = cadd(t5w, t7w), ee = csub(t5w, t7w);
    float2 v3 = INV ? make_float2(-ee.y, ee.x) : make_float2(ee.y, -ee.x);
    x[1] = cadd(v0, v1); x[3] = cadd(v2, v3);
    if (!PRUNE) { x[5] = csub(v0, v1); x[7] = csub(v2, v3); }
}

__device__ __forceinline__ void make_tw(int o, float2* tw) {
    float s, co;
    sincosf(-TWO_PI * (float)o / 64.f, &s, &co);
    tw[0] = make_float2(co, s);
#pragma unroll
    for (int k = 1; k < 7; ++k) tw[k] = cmulf(tw[k - 1], tw[0]);
}

// 64-pt FFT over one line by an 8-lane group. In: reg j = point (8j+o).
// Out: reg m = point (o+8m) (PRUNE: only m<4 valid). Natural order.
template<bool INV, bool COL, bool HALF, bool PRUNE>
__device__ __forceinline__ void fft64(float2* a, float2* r, const float2* tw,
                                      int o, int line) {
    dft8<INV, HALF, false>(r);
#pragma unroll
    for (int k = 1; k < 8; ++k) {
        float2 w = tw[k - 1];
        if (INV) w.y = -w.y;
        r[k] = cmulf(r[k], w);
    }
#pragma unroll
    for (int m = 0; m < 8; ++m) {
        int s = 8 * o + m;
        a[COL ? swz(s, line) : swz(line, s)] = r[m];
    }
#pragma unroll
    for (int j = 0; j < 8; ++j) {
        int s = 8 * j + o;
        r[j] = a[COL ? swz(s, line) : swz(line, s)];
    }
    dft8<INV, false, PRUNE>(r);
}

// ---------------- P1: fused SSM impulse response + spectrum -------------------
// Block = channel d, 512 thr = 8 warps = 4 dirs x 2 n-halves.
// lane = jg(0..7, 4 cols each) + 8*n8. Affine Kogge-Stone scan with CONSTANT
// ratio A1^4 (masked per-lane coeffs A1^4/A1^8/A1^16) via DPP row_shr —
// no linear-map composition, no bpermute. i==0 peeled; row0/col0 go to side
// buffers (no atomics); edge factors applied in the fold pass.
__global__ __launch_bounds__(512) void ssm_gf(
        const float* __restrict__ Aang, const float* __restrict__ Arad,
        const float* __restrict__ B1p, const float* __restrict__ B2p,
        const float* __restrict__ C1p, const float* __restrict__ C2p,
        float2* __restrict__ Gf) {
    __shared__ float2 a[4096];
    __shared__ float row0buf[4][2][64];   // [t][nh][cc]  (i==0 writes)
    __shared__ float col0buf[2][2][64];   // [t>>1][nh][rr] (col==0, i>=1)
    int d = blockIdx.x;
    int tid = threadIdx.x;
    int w = tid >> 6;
    int t = w & 3;
    int nh = w >> 2;
    int lane = tid & 63;
    int jg = lane & 7;
    int n8 = lane >> 3;
    int n = n8 + 8 * nh;
    int ch = t * 768 + d;
    int gid = ch * 16 + n;

    for (int e = tid; e < 4096; e += 512) a[e] = make_float2(0.f, 0.f);
    (&row0buf[0][0][0])[tid] = 0.f;
    if (tid < 256) (&col0buf[0][0][0])[tid] = 0.f;

    float ar[4], ai[4];
#pragma unroll
    for (int q = 0; q < 4; ++q) {
        float ang = sigm(Aang[q * 49152 + gid]) * TWO_PI;
        float rad = sigm(Arad[q * 49152 + gid]);
        float s, co;
        sincosf(ang, &s, &co);
        ar[q] = rad * co; ai[q] = rad * s;
    }
    float a1r = ar[0], a1i = ai[0], a2r = ar[1], a2i = ai[1];
    float a3r = ar[2], a3i = ai[2], a4r = ar[3], a4i = ai[3];
    float p2r = a1r * a1r - a1i * a1i, p2i = 2.f * a1r * a1i;          // A1^2
    float p3r = a1r * p2r - a1i * p2i, p3i = a1r * p2i + a1i * p2r;    // A1^3
    float p4r = p2r * p2r - p2i * p2i, p4i = 2.f * p2r * p2i;          // A1^4
    float p8r = p4r * p4r - p4i * p4i, p8i = 2.f * p4r * p4i;          // A1^8
    float p16r = p8r * p8r - p8i * p8i, p16i = 2.f * p8r * p8i;        // A1^16
    // masked scan coefficients
    float cz1r = (jg >= 1) ? p4r : 0.f,  cz1i = (jg >= 1) ? p4i : 0.f;
    float cz2r = (jg >= 2) ? p8r : 0.f,  cz2i = (jg >= 2) ? p8i : 0.f;
    float cz4r = (jg >= 4) ? p16r : 0.f, cz4i = (jg >= 4) ? p16i : 0.f;

    const float2* B1v = (const float2*)B1p;
    const float2* B2v = (const float2*)B2p;
    const float2* C1v = (const float2*)C1p;
    const float2* C2v = (const float2*)C2p;
    float2 b1 = B1v[gid], b2 = B2v[gid], c1 = C1v[gid], c2 = C2v[gid];
    float b1r = sigm(b1.x), b1i = sigm(b1.y);
    float b2r = sigm(b2.x), b2i = sigm(b2.y);
    float c1r = c1.x, c1i = c1.y, c2r = c2.x, c2i = c2.y;

    // eb = A1^{4*jg} * b1  (entry term for the impulse row)
    float pwr = 1.f, pwi = 0.f;
    if (jg & 1) { pwr = p4r; pwi = p4i; }
    if (jg & 2) { float tr = pwr * p8r - pwi * p8i;  pwi = pwr * p8i + pwi * p8r;  pwr = tr; }
    if (jg & 4) { float tr = pwr * p16r - pwi * p16i; pwi = pwr * p16i + pwi * p16r; pwr = tr; }
    float ebr = pwr * b1r - pwi * b1i, ebi = pwr * b1i + pwi * b1r;

    int bb0 = n8 & 1, bb1 = (n8 >> 1) & 1;
    int col = 4 * jg + 2 * bb0 + bb1;
    int ccl = (t & 2) ? ((64 - col) & 63) : col;

    __syncthreads();

    float xvr[4], xvi[4], xhr[4], xhi[4];
#pragma unroll
    for (int m = 0; m < 4; ++m) { xvr[m] = 0.f; xvi[m] = 0.f; xhr[m] = 0.f; xhi[m] = 0.f; }

    auto body = [&](int i, bool is0) {
        // vertical: xv = A3*xh_prev + A4*xv_prev
#pragma unroll
        for (int m = 0; m < 4; ++m) {
            float nr = a3r * xhr[m] - a3i * xhi[m] + a4r * xvr[m] - a4i * xvi[m];
            float ni = a3r * xhi[m] + a3i * xhr[m] + a4r * xvi[m] + a4i * xvr[m];
            xvr[m] = nr; xvi[m] = ni;
        }
        if (is0 && jg == 0) { xvr[0] += b2r; xvi[0] += b2i; }
        // zero-entry chain + segment load
        float g1r = a2r * xvr[0] - a2i * xvi[0];
        float g1i = a2r * xvi[0] + a2i * xvr[0];
        float g2r = a1r * g1r - a1i * g1i + a2r * xvr[1] - a2i * xvi[1];
        float g2i = a1r * g1i + a1i * g1r + a2r * xvi[1] + a2i * xvr[1];
        float g3r = a1r * g2r - a1i * g2i + a2r * xvr[2] - a2i * xvi[2];
        float g3i = a1r * g2i + a1i * g2r + a2r * xvi[2] + a2i * xvr[2];
        float ldr = a1r * g3r - a1i * g3i + a2r * xvr[3] - a2i * xvi[3];
        float ldi = a1r * g3i + a1i * g3r + a2r * xvi[3] + a2i * xvr[3];
        // affine Kogge-Stone scan, constant ratio, DPP shifts
        float Vr = ldr, Vi = ldi, sr, si;
        sr = dpp0<DPP_SHR1>(Vr); si = dpp0<DPP_SHR1>(Vi);
        Vr += cz1r * sr - cz1i * si; Vi += cz1r * si + cz1i * sr;
        sr = dpp0<DPP_SHR2>(Vr); si = dpp0<DPP_SHR2>(Vi);
        Vr += cz2r * sr - cz2i * si; Vi += cz2r * si + cz2i * sr;
        sr = dpp0<DPP_SHR4>(Vr); si = dpp0<DPP_SHR4>(Vi);
        Vr += cz4r * sr - cz4i * si; Vi += cz4r * si + cz4i * sr;
        // exclusive entry value
        float Er = dpp0<DPP_SHR1>(Vr), Ei = dpp0<DPP_SHR1>(Vi);
        Er = (jg == 0) ? 0.f : Er; Ei = (jg == 0) ? 0.f : Ei;
        if (is0) { Er += ebr; Ei += ebi; }
        // xh[m] = A1^m * E + g[m]
        xhr[0] = Er; xhi[0] = Ei;
        xhr[1] = a1r * Er - a1i * Ei + g1r;  xhi[1] = a1r * Ei + a1i * Er + g1i;
        xhr[2] = p2r * Er - p2i * Ei + g2r;  xhi[2] = p2r * Ei + p2i * Er + g2i;
        xhr[3] = p3r * Er - p3i * Ei + g3r;  xhi[3] = p3r * Ei + p3i * Er + g3i;
        // C-dot per column
        float v0 = c1r * xhr[0] - c1i * xhi[0] + c2r * xvr[0] - c2i * xvi[0];
        float v1 = c1r * xhr[1] - c1i * xhi[1] + c2r * xvr[1] - c2i * xvi[1];
        float v2 = c1r * xhr[2] - c1i * xhi[2] + c2r * xvr[2] - c2i * xvi[2];
        float v3 = c1r * xhr[3] - c1i * xhi[3] + c2r * xvr[3] - c2i * xvi[3];
        // multi-value reduce over n8: xor8 (DPP ror8), xor16 (ds_swizzle), xor32 (shfl)
        float s0 = bb0 ? v0 : v2, s1 = bb0 ? v1 : v3;
        float r0 = dpp0<DPP_ROR8>(s0), r1 = dpp0<DPP_ROR8>(s1);
        float q0 = (bb0 ? v2 : v0) + r0;
        float q1 = (bb0 ? v3 : v1) + r1;
        float s2 = bb1 ? q0 : q1;
        float r2 = swz_xor16(s2);
        float qq = (bb1 ? q1 : q0) + r2;
        qq += __shfl_xor(qq, 32, 64);
        if (n8 < 4) {
            if (is0) {
                row0buf[t][nh][ccl] = qq;
            } else if (col == 0) {
                col0buf[t >> 1][nh][(t & 1) ? (64 - i) : i] = qq;
            } else {
                int rr_ = (t & 1) ? (64 - i) : i;
                ((float*)&a[swz(rr_, ccl)])[nh] = qq;
            }
        }
    };
    body(0, true);
#pragma unroll 1
    for (int i = 1; i < 32; ++i) body(i, false);

    __syncthreads();
    // fold: combine nh components + edge buffers, apply boundary factors
    for (int e = tid; e < 4096; e += 512) {
        int r = e >> 6, cm = e & 63;
        int c = cm ^ ((r ^ (r << 3)) & 63);
        float2 cv = a[e];
        float v = cv.x + cv.y;
        if (r == 0) {
            v += row0buf[0][0][c] + row0buf[0][1][c] + row0buf[1][0][c] + row0buf[1][1][c]
               + row0buf[2][0][c] + row0buf[2][1][c] + row0buf[3][0][c] + row0buf[3][1][c];
        } else if (c == 0) {
            v += col0buf[0][0][r] + col0buf[0][1][r] + col0buf[1][0][r] + col0buf[1][1][r];
        }
        float f = 0.25f;
        if (r == 0) f *= 2.f;
        if (c == 0) f *= 2.f;
        if (r == 0 && c == 0) f *= 0.25f;
        a[e] = make_float2(f * v, 0.f);
    }
    __syncthreads();
    // 2D forward FFT -> Gf (single sweeps, 64 groups)
    int o = tid & 7;
    float2 tw[7];
    make_tw(o, tw);
    {
        int row = tid >> 3;
        float2 r[8];
#pragma unroll
        for (int j = 0; j < 8; ++j) r[j] = a[swz(row, 8 * j + o)];
        fft64<false, false, false, false>(a, r, tw, o, row);
#pragma unroll
        for (int m = 0; m < 8; ++m) a[swz(row, o + 8 * m)] = r[m];
    }
    __syncthreads();
    {
        int cc = tid >> 3;
        float2 r[8];
#pragma unroll
        for (int j = 0; j < 8; ++j) r[j] = a[swz(8 * j + o, cc)];
        fft64<false, true, false, false>(a, r, tw, o, cc);
#pragma unroll
        for (int m = 0; m < 8; ++m) Gf[d * 4096 + gfidx(o, m, cc)] = r[m];
    }
}

// ---------------- P2: x (S,BD) -> xT (BD,S), 64x64 tiles ----------------------
__global__ __launch_bounds__(256) void transpose_in(const float* __restrict__ x,
                                                    float* __restrict__ xT) {
    __shared__ float t[64][65];
    int bR = blockIdx.x % 192, bS = blockIdx.x / 192;
    int r0 = bR * 64, s0 = bS * 64;
    int c = threadIdx.x & 63, w = threadIdx.x >> 6;
#pragma unroll
    for (int k = 0; k < 16; ++k) {
        int row = w + 4 * k;
        t[row][c] = x[(size_t)(s0 + row) * 12288 + r0 + c];
    }
    __syncthreads();
#pragma unroll
    for (int k = 0; k < 16; ++k) {
        int row = w + 4 * k;
        xT[(size_t)(r0 + row) * 1024 + s0 + c] = t[c][row];
    }
}

// ---------------- P4: xT (BD,S) -> out (S,BD), 64x64 tiles --------------------
__global__ __launch_bounds__(256) void transpose_out(const float* __restrict__ xT,
                                                     float* __restrict__ out) {
    __shared__ float t[64][65];
    int bR = blockIdx.x % 192, bS = blockIdx.x / 192;
    int r0 = bR * 64, s0 = bS * 64;
    int c = threadIdx.x & 63, w = threadIdx.x >> 6;
#pragma unroll
    for (int k = 0; k < 16; ++k) {
        int row = w + 4 * k;
        t[row][c] = xT[(size_t)(r0 + row) * 1024 + s0 + c];
    }
    __syncthreads();
#pragma unroll
    for (int k = 0; k < 16; ++k) {
        int row = w + 4 * k;
        out[(size_t)(s0 + row) * 12288 + r0 + c] = t[c][row];
    }
}

// ---------------- P3: FFT conv, two batch images packed re/im -----------------
__global__ __launch_bounds__(256) void conv_fft(
        const float* __restrict__ x, float* __restrict__ xT,
        const float2* __restrict__ Gf, const float* __restrict__ omega,
        float* __restrict__ out, int useT) {
    __shared__ float2 a[4096];
    // XCD-chunked swizzle: same-d blocks (8 bpairs) colocate on one XCD.
    int bid = (blockIdx.x & 7) * 768 + (blockIdx.x >> 3);
    int d = bid >> 3, b = (bid & 7) * 2;
    int tid = threadIdx.x;
    int o = tid & 7;
    float2 tw[7];
    make_tw(o, tw);
    const size_t base0 = (size_t)(b * 768 + d) * 1024;
    const size_t base1 = (size_t)((b + 1) * 768 + d) * 1024;
    // ---- forward rows (32 nonzero rows == 32 groups, one shot) ----
    {
        int row = tid >> 3;
        float2 r[8];
#pragma unroll
        for (int j = 0; j < 4; ++j) {
            int s2 = row * 32 + 8 * j + o;
            if (useT) r[j] = make_float2(xT[base0 + s2], xT[base1 + s2]);
            else      r[j] = make_float2(x[s2 * 12288 + b * 768 + d],
                                         x[s2 * 12288 + (b + 1) * 768 + d]);
        }
#pragma unroll
        for (int j = 4; j < 8; ++j) r[j] = make_float2(0.f, 0.f);
        fft64<false, false, true, false>(a, r, tw, o, row);
#pragma unroll
        for (int m = 0; m < 8; ++m) a[swz(row, o + 8 * m)] = r[m];
    }
    __syncthreads();
    // ---- columns: fwd FFT ⊙ Gf, inv FFT — fused in registers ----
#pragma unroll 1
    for (int sw = 0; sw < 2; ++sw) {
        int c = sw * 32 + (tid >> 3);
        float2 r[8];
#pragma unroll
        for (int j = 0; j < 4; ++j) r[j] = a[swz(8 * j + o, c)];
#pragma unroll
        for (int j = 4; j < 8; ++j) r[j] = make_float2(0.f, 0.f);
        fft64<false, true, true, false>(a, r, tw, o, c);
#pragma unroll
        for (int m = 0; m < 8; ++m) {
            r[m] = cmulf(r[m], Gf[d * 4096 + gfidx(o, m, c)]);
        }
        fft64<true, true, false, true>(a, r, tw, o, c);
#pragma unroll
        for (int m = 0; m < 4; ++m) a[swz(o + 8 * m, c)] = r[m];
    }
    __syncthreads();
    // ---- inverse rows + epilogue ----
    {
        int row = tid >> 3;
        float2 r[8];
#pragma unroll
        for (int j = 0; j < 8; ++j) r[j] = a[swz(row, 8 * j + o)];
        fft64<true, false, false, true>(a, r, tw, o, row);
        float w = omega[d];
        const float inv = 1.0f / 4096.0f;
#pragma unroll
        for (int m = 0; m < 4; ++m) {
            int cc = o + 8 * m;
            int s2 = row * 32 + cc;
            float xa, xb;
            if (useT) { xa = xT[base0 + s2]; xb = xT[base1 + s2]; }
            else {
                xa = x[s2 * 12288 + b * 768 + d];
                xb = x[s2 * 12288 + (b + 1) * 768 + d];
            }
            float ya = r[m].x * inv + xa * w;
            float yb = r[m].y * inv + xb * w;
            float oa = ya / (1.0f + expf(-ya));
            float ob = yb / (1.0f + expf(-yb));
            if (useT) {
                xT[base0 + s2] = oa;        // overwrite own row (outT alias)
                xT[base1 + s2] = ob;
            } else {
                out[s2 * 12288 + b * 768 + d] = oa;
                out[s2 * 12288 + (b + 1) * 768 + d] = ob;
            }
        }
    }
}

extern "C" void kernel_launch(void* const* d_in, const int* in_sizes, int n_in,
                              void* d_out, int out_size, void* d_ws, size_t ws_size,
                              hipStream_t stream) {
    const float* x     = (const float*)d_in[0];
    const float* Aang  = (const float*)d_in[1];
    const float* Arad  = (const float*)d_in[2];
    const float* B1p   = (const float*)d_in[3];
    const float* B2p   = (const float*)d_in[4];
    const float* C1p   = (const float*)d_in[5];
    const float* C2p   = (const float*)d_in[6];
    const float* omega = (const float*)d_in[7];
    float* out = (float*)d_out;
    char* ws = (char*)d_ws;

    float2* Gf = (float2*)ws;                       // 25,165,824 B
    float*  xT = (float*)(ws + 25165824);           // 50,331,648 B (in+out alias)
    int useT = (ws_size >= (size_t)75497472) ? 1 : 0;

    ssm_gf<<<768, 512, 0, stream>>>(Aang, Arad, B1p, B2p, C1p, C2p, Gf);
    if (useT) transpose_in<<<3072, 256, 0, stream>>>(x, xT);
    conv_fft<<<6144, 256, 0, stream>>>(x, xT, Gf, omega, out, useT);
    if (useT) transpose_out<<<3072, 256, 0, stream>>>(xT, out);
}

// Round 9
// 153.671 us; speedup vs baseline: 2.7191x; 1.0950x over previous
//
#include <hip/hip_runtime.h>
#include <cmath>

#define TWO_PI 6.283185307179586476925f

typedef float f2 __attribute__((ext_vector_type(2)));

__device__ __forceinline__ float sigm(float v) { return 1.0f / (1.0f + __expf(-v)); }
__device__ __forceinline__ f2 mnegi(f2 v) { return (f2){v.y, -v.x}; }   // v * (-i)
__device__ __forceinline__ f2 mposi(f2 v) { return (f2){-v.y, v.x}; }   // v * (+i)
__device__ __forceinline__ f2 cmulf(f2 a, f2 b) {
    return (f2){a.x, a.x} * b + (f2){a.y, a.y} * mposi(b);
}

// DPP lane move within 16-lane rows; invalid sources read 0 (bound_ctrl).
template<int CTRL>
__device__ __forceinline__ float dpp0(float v) {
    return __int_as_float(__builtin_amdgcn_update_dpp(
        0, __float_as_int(v), CTRL, 0xf, 0xf, true));
}
#define DPP_SHR1 0x111
#define DPP_SHR2 0x112
#define DPP_SHR4 0x114
#define DPP_ROR8 0x128

__device__ __forceinline__ float swz_xor16(float v) {
    return __int_as_float(__builtin_amdgcn_ds_swizzle(__float_as_int(v), 0x401F));
}

// XOR-swizzled cell address for the 64x64 f2 tile.
__device__ __forceinline__ int swz(int r, int c) {
    return (r << 6) | (c ^ ((r ^ (r << 3)) & 63));
}

// Gf layout: element (freq row u = o+8m, freq col c) at  o + 8*c + 512*m.
__device__ __forceinline__ int gfidx(int o, int m, int c) {
    return o + (c << 3) + (m << 9);
}

// In-register 8-point DFT. INV: conj twiddles. HALF: x[4..7] zero. PRUNE: skip x[4..7] outs.
template<bool INV, bool HALF, bool PRUNE>
__device__ __forceinline__ void dft8(f2* x) {
    const float RS = 0.70710678118654752440f;
    f2 t0, t1, t2, t3, t4, t5, t6, t7;
    if (HALF) {
        t0 = x[0]; t4 = x[0]; t1 = x[1]; t5 = x[1];
        t2 = x[2]; t6 = x[2]; t3 = x[3]; t7 = x[3];
    } else {
        t0 = x[0] + x[4]; t4 = x[0] - x[4];
        t1 = x[1] + x[5]; t5 = x[1] - x[5];
        t2 = x[2] + x[6]; t6 = x[2] - x[6];
        t3 = x[3] + x[7]; t7 = x[3] - x[7];
    }
    f2 t5w, t6w, t7w;
    if (!INV) {
        t5w = RS * (t5 + mnegi(t5));
        t6w = mnegi(t6);
        t7w = RS * (mnegi(t7) - t7);
    } else {
        t5w = RS * (t5 - mnegi(t5));
        t6w = mposi(t6);
        t7w = RS * (mposi(t7) - t7);
    }
    f2 u0 = t0 + t2, u2 = t0 - t2, u1 = t1 + t3, dd = t1 - t3;
    f2 u3 = INV ? mposi(dd) : mnegi(dd);
    x[0] = u0 + u1; x[2] = u2 + u3;
    if (!PRUNE) { x[4] = u0 - u1; x[6] = u2 - u3; }
    f2 v0 = t4 + t6w, v2 = t4 - t6w, v1 = t5w + t7w, ee = t5w - t7w;
    f2 v3 = INV ? mposi(ee) : mnegi(ee);
    x[1] = v0 + v1; x[3] = v2 + v3;
    if (!PRUNE) { x[5] = v0 - v1; x[7] = v2 - v3; }
}

__device__ __forceinline__ void make_tw(int o, f2* tw) {
    float s, co;
    __sincosf(-TWO_PI * (float)o / 64.f, &s, &co);
    tw[0] = (f2){co, s};
#pragma unroll
    for (int k = 1; k < 7; ++k) tw[k] = cmulf(tw[k - 1], tw[0]);
}

// 64-pt FFT over one line by an 8-lane group. In: reg j = point (8j+o).
// Out: reg m = point (o+8m) (PRUNE: only m<4 valid). Natural order.
template<bool INV, bool COL, bool HALF, bool PRUNE>
__device__ __forceinline__ void fft64(f2* a, f2* r, const f2* tw,
                                      int o, int line) {
    dft8<INV, HALF, false>(r);
#pragma unroll
    for (int k = 1; k < 8; ++k) {
        f2 w = tw[k - 1];
        if (INV) w.y = -w.y;
        r[k] = cmulf(r[k], w);
    }
#pragma unroll
    for (int m = 0; m < 8; ++m) {
        int s = 8 * o + m;
        a[COL ? swz(s, line) : swz(line, s)] = r[m];
    }
#pragma unroll
    for (int j = 0; j < 8; ++j) {
        int s = 8 * j + o;
        r[j] = a[COL ? swz(s, line) : swz(line, s)];
    }
    dft8<INV, false, PRUNE>(r);
}

// ---------------- P1: fused SSM+spectrum (blocks <768) + input transpose ------
// ssm blocks: channel d, 512 thr = 4 dirs x 2 n-halves; DPP affine scan.
// transpose blocks (>=768): x (S,BD) -> xT (BD,S), 64x64 tiles, 512 thr.
// Memory-bound transpose overlaps VALU-bound recurrence in one launch.
__global__ __launch_bounds__(512) void ssm_tin(
        const float* __restrict__ Aang, const float* __restrict__ Arad,
        const float* __restrict__ B1p, const float* __restrict__ B2p,
        const float* __restrict__ C1p, const float* __restrict__ C2p,
        f2* __restrict__ Gf, const float* __restrict__ x,
        float* __restrict__ xT) {
    __shared__ __align__(16) char smem[35840];
    int tid = threadIdx.x;

    if (blockIdx.x >= 768) {
        // ---- input transpose path ----
        float (*tt)[65] = (float (*)[65])smem;
        int bb = blockIdx.x - 768;
        int bR = bb % 192, bS = bb / 192;
        int r0 = bR * 64, s0 = bS * 64;
        int c = tid & 63, w = tid >> 6;
#pragma unroll
        for (int k = 0; k < 8; ++k) {
            int row = w + 8 * k;
            tt[row][c] = x[(size_t)(s0 + row) * 12288 + r0 + c];
        }
        __syncthreads();
#pragma unroll
        for (int k = 0; k < 8; ++k) {
            int row = w + 8 * k;
            xT[(size_t)(r0 + row) * 1024 + s0 + c] = tt[c][row];
        }
        return;
    }

    f2* a = (f2*)smem;                          // 32768 B
    float* row0 = (float*)(smem + 32768);       // [t][nh][c]  2048 B
    float* col0 = (float*)(smem + 34816);       // [t>>1][nh][r] 1024 B
    int d = blockIdx.x;
    int w = tid >> 6;
    int t = w & 3;
    int nh = w >> 2;
    int lane = tid & 63;
    int jg = lane & 7;
    int n8 = lane >> 3;
    int n = n8 + 8 * nh;
    int ch = t * 768 + d;
    int gid = ch * 16 + n;

    for (int e = tid; e < 4096; e += 512) a[e] = (f2){0.f, 0.f};
    row0[tid] = 0.f;
    if (tid < 256) col0[tid] = 0.f;

    float ar[4], ai[4];
#pragma unroll
    for (int q = 0; q < 4; ++q) {
        float ang = sigm(Aang[q * 49152 + gid]) * TWO_PI;
        float rad = sigm(Arad[q * 49152 + gid]);
        float s, co;
        __sincosf(ang, &s, &co);
        ar[q] = rad * co; ai[q] = rad * s;
    }
    float a1r = ar[0], a1i = ai[0], a2r = ar[1], a2i = ai[1];
    float a3r = ar[2], a3i = ai[2], a4r = ar[3], a4i = ai[3];
    float p2r = a1r * a1r - a1i * a1i, p2i = 2.f * a1r * a1i;
    float p3r = a1r * p2r - a1i * p2i, p3i = a1r * p2i + a1i * p2r;
    float p4r = p2r * p2r - p2i * p2i, p4i = 2.f * p2r * p2i;
    float p8r = p4r * p4r - p4i * p4i, p8i = 2.f * p4r * p4i;
    float p16r = p8r * p8r - p8i * p8i, p16i = 2.f * p8r * p8i;
    float cz1r = (jg >= 1) ? p4r : 0.f,  cz1i = (jg >= 1) ? p4i : 0.f;
    float cz2r = (jg >= 2) ? p8r : 0.f,  cz2i = (jg >= 2) ? p8i : 0.f;
    float cz4r = (jg >= 4) ? p16r : 0.f, cz4i = (jg >= 4) ? p16i : 0.f;

    const float2* B1v = (const float2*)B1p;
    const float2* B2v = (const float2*)B2p;
    const float2* C1v = (const float2*)C1p;
    const float2* C2v = (const float2*)C2p;
    float2 b1 = B1v[gid], b2 = B2v[gid], c1 = C1v[gid], c2 = C2v[gid];
    float b1r = sigm(b1.x), b1i = sigm(b1.y);
    float b2r = sigm(b2.x), b2i = sigm(b2.y);
    float c1r = c1.x, c1i = c1.y, c2r = c2.x, c2i = c2.y;

    float pwr = 1.f, pwi = 0.f;
    if (jg & 1) { pwr = p4r; pwi = p4i; }
    if (jg & 2) { float tr = pwr * p8r - pwi * p8i;  pwi = pwr * p8i + pwi * p8r;  pwr = tr; }
    if (jg & 4) { float tr = pwr * p16r - pwi * p16i; pwi = pwr * p16i + pwi * p16r; pwr = tr; }
    float ebr = pwr * b1r - pwi * b1i, ebi = pwr * b1i + pwi * b1r;

    int bb0 = n8 & 1, bb1 = (n8 >> 1) & 1;
    int col = 4 * jg + 2 * bb0 + bb1;
    int ccl = (t & 2) ? ((64 - col) & 63) : col;

    __syncthreads();

    float xvr[4], xvi[4], xhr[4], xhi[4];
#pragma unroll
    for (int m = 0; m < 4; ++m) { xvr[m] = 0.f; xvi[m] = 0.f; xhr[m] = 0.f; xhi[m] = 0.f; }

    auto body = [&](int i, bool is0) {
#pragma unroll
        for (int m = 0; m < 4; ++m) {
            float nr = a3r * xhr[m] - a3i * xhi[m] + a4r * xvr[m] - a4i * xvi[m];
            float ni = a3r * xhi[m] + a3i * xhr[m] + a4r * xvi[m] + a4i * xvr[m];
            xvr[m] = nr; xvi[m] = ni;
        }
        if (is0 && jg == 0) { xvr[0] += b2r; xvi[0] += b2i; }
        float g1r = a2r * xvr[0] - a2i * xvi[0];
        float g1i = a2r * xvi[0] + a2i * xvr[0];
        float g2r = a1r * g1r - a1i * g1i + a2r * xvr[1] - a2i * xvi[1];
        float g2i = a1r * g1i + a1i * g1r + a2r * xvi[1] + a2i * xvr[1];
        float g3r = a1r * g2r - a1i * g2i + a2r * xvr[2] - a2i * xvi[2];
        float g3i = a1r * g2i + a1i * g2r + a2r * xvi[2] + a2i * xvr[2];
        float ldr = a1r * g3r - a1i * g3i + a2r * xvr[3] - a2i * xvi[3];
        float ldi = a1r * g3i + a1i * g3r + a2r * xvi[3] + a2i * xvr[3];
        float Vr = ldr, Vi = ldi, sr, si;
        sr = dpp0<DPP_SHR1>(Vr); si = dpp0<DPP_SHR1>(Vi);
        Vr += cz1r * sr - cz1i * si; Vi += cz1r * si + cz1i * sr;
        sr = dpp0<DPP_SHR2>(Vr); si = dpp0<DPP_SHR2>(Vi);
        Vr += cz2r * sr - cz2i * si; Vi += cz2r * si + cz2i * sr;
        sr = dpp0<DPP_SHR4>(Vr); si = dpp0<DPP_SHR4>(Vi);
        Vr += cz4r * sr - cz4i * si; Vi += cz4r * si + cz4i * sr;
        float Er = dpp0<DPP_SHR1>(Vr), Ei = dpp0<DPP_SHR1>(Vi);
        Er = (jg == 0) ? 0.f : Er; Ei = (jg == 0) ? 0.f : Ei;
        if (is0) { Er += ebr; Ei += ebi; }
        xhr[0] = Er; xhi[0] = Ei;
        xhr[1] = a1r * Er - a1i * Ei + g1r;  xhi[1] = a1r * Ei + a1i * Er + g1i;
        xhr[2] = p2r * Er - p2i * Ei + g2r;  xhi[2] = p2r * Ei + p2i * Er + g2i;
        xhr[3] = p3r * Er - p3i * Ei + g3r;  xhi[3] = p3r * Ei + p3i * Er + g3i;
        float v0 = c1r * xhr[0] - c1i * xhi[0] + c2r * xvr[0] - c2i * xvi[0];
        float v1 = c1r * xhr[1] - c1i * xhi[1] + c2r * xvr[1] - c2i * xvi[1];
        float v2 = c1r * xhr[2] - c1i * xhi[2] + c2r * xvr[2] - c2i * xvi[2];
        float v3 = c1r * xhr[3] - c1i * xhi[3] + c2r * xvr[3] - c2i * xvi[3];
        float s0 = bb0 ? v0 : v2, s1 = bb0 ? v1 : v3;
        float r0 = dpp0<DPP_ROR8>(s0), r1 = dpp0<DPP_ROR8>(s1);
        float q0 = (bb0 ? v2 : v0) + r0;
        float q1 = (bb0 ? v3 : v1) + r1;
        float s2 = bb1 ? q0 : q1;
        float r2 = swz_xor16(s2);
        float qq = (bb1 ? q1 : q0) + r2;
        qq += __shfl_xor(qq, 32, 64);
        if (n8 < 4) {
            if (is0) {
                row0[(((t << 1) | nh) << 6) | ccl] = qq;
            } else if (col == 0) {
                col0[((((t >> 1) << 1) | nh) << 6) | ((t & 1) ? (64 - i) : i)] = qq;
            } else {
                int rr_ = (t & 1) ? (64 - i) : i;
                ((float*)&a[swz(rr_, ccl)])[nh] = qq;
            }
        }
    };
    body(0, true);
#pragma unroll 1
    for (int i = 1; i < 32; ++i) body(i, false);

    __syncthreads();
    // fold: combine nh components + edge buffers, apply boundary factors
    for (int e = tid; e < 4096; e += 512) {
        int r = e >> 6, cm = e & 63;
        int c = cm ^ ((r ^ (r << 3)) & 63);
        f2 cv = a[e];
        float v = cv.x + cv.y;
        if (r == 0) {
            v += row0[c] + row0[64 + c] + row0[128 + c] + row0[192 + c]
               + row0[256 + c] + row0[320 + c] + row0[384 + c] + row0[448 + c];
        } else if (c == 0) {
            v += col0[r] + col0[64 + r] + col0[128 + r] + col0[192 + r];
        }
        float f = 0.25f;
        if (r == 0) f *= 2.f;
        if (c == 0) f *= 2.f;
        if (r == 0 && c == 0) f *= 0.25f;
        a[e] = (f2){f * v, 0.f};
    }
    __syncthreads();
    // 2D forward FFT -> Gf (single sweeps, 64 groups)
    int o = tid & 7;
    f2 tw[7];
    make_tw(o, tw);
    {
        int row = tid >> 3;
        f2 r[8];
#pragma unroll
        for (int j = 0; j < 8; ++j) r[j] = a[swz(row, 8 * j + o)];
        fft64<false, false, false, false>(a, r, tw, o, row);
#pragma unroll
        for (int m = 0; m < 8; ++m) a[swz(row, o + 8 * m)] = r[m];
    }
    __syncthreads();
    {
        int cc = tid >> 3;
        f2 r[8];
#pragma unroll
        for (int j = 0; j < 8; ++j) r[j] = a[swz(8 * j + o, cc)];
        fft64<false, true, false, false>(a, r, tw, o, cc);
#pragma unroll
        for (int m = 0; m < 8; ++m) Gf[d * 4096 + gfidx(o, m, cc)] = r[m];
    }
}

// ---------------- P3: FFT conv, two batch images packed re/im, 512 thr --------
__global__ __launch_bounds__(512) void conv_fft(
        const float* __restrict__ x, float* __restrict__ xT,
        const f2* __restrict__ Gf, const float* __restrict__ omega,
        float* __restrict__ out, int useT) {
    __shared__ f2 a[4096];
    // XCD-chunked swizzle: same-d blocks (8 bpairs) colocate on one XCD.
    int bid = (blockIdx.x & 7) * 768 + (blockIdx.x >> 3);
    int d = bid >> 3, b = (bid & 7) * 2;
    int tid = threadIdx.x;
    int o = tid & 7, grp = tid >> 3;      // grp 0..63
    f2 tw[7];
    make_tw(o, tw);
    const size_t base0 = (size_t)(b * 768 + d) * 1024;
    const size_t base1 = (size_t)((b + 1) * 768 + d) * 1024;
    // ---- forward rows (32 nonzero rows; groups 32..63 idle) ----
    if (grp < 32) {
        int row = grp;
        f2 r[8];
#pragma unroll
        for (int j = 0; j < 4; ++j) {
            int s2 = row * 32 + 8 * j + o;
            if (useT) r[j] = (f2){xT[base0 + s2], xT[base1 + s2]};
            else      r[j] = (f2){x[s2 * 12288 + b * 768 + d],
                                  x[s2 * 12288 + (b + 1) * 768 + d]};
        }
#pragma unroll
        for (int j = 4; j < 8; ++j) r[j] = (f2){0.f, 0.f};
        fft64<false, false, true, false>(a, r, tw, o, row);
#pragma unroll
        for (int m = 0; m < 8; ++m) a[swz(row, o + 8 * m)] = r[m];
    }
    __syncthreads();
    // ---- columns (all 64 groups): fwd FFT ⊙ Gf, inv FFT in registers ----
    {
        int c = grp;
        f2 r[8];
#pragma unroll
        for (int j = 0; j < 4; ++j) r[j] = a[swz(8 * j + o, c)];
#pragma unroll
        for (int j = 4; j < 8; ++j) r[j] = (f2){0.f, 0.f};
        fft64<false, true, true, false>(a, r, tw, o, c);
#pragma unroll
        for (int m = 0; m < 8; ++m) {
            r[m] = cmulf(r[m], Gf[d * 4096 + gfidx(o, m, c)]);
        }
        fft64<true, true, false, true>(a, r, tw, o, c);
#pragma unroll
        for (int m = 0; m < 4; ++m) a[swz(o + 8 * m, c)] = r[m];
    }
    __syncthreads();
    // ---- inverse rows + epilogue (groups 32..63 idle) ----
    if (grp < 32) {
        int row = grp;
        f2 r[8];
#pragma unroll
        for (int j = 0; j < 8; ++j) r[j] = a[swz(row, 8 * j + o)];
        fft64<true, false, false, true>(a, r, tw, o, row);
        float w = omega[d];
        const float inv = 1.0f / 4096.0f;
#pragma unroll
        for (int m = 0; m < 4; ++m) {
            int cc = o + 8 * m;
            int s2 = row * 32 + cc;
            float xa, xb;
            if (useT) { xa = xT[base0 + s2]; xb = xT[base1 + s2]; }
            else {
                xa = x[s2 * 12288 + b * 768 + d];
                xb = x[s2 * 12288 + (b + 1) * 768 + d];
            }
            float ya = r[m].x * inv + xa * w;
            float yb = r[m].y * inv + xb * w;
            float oa = ya / (1.0f + __expf(-ya));
            float ob = yb / (1.0f + __expf(-yb));
            if (useT) {
                xT[base0 + s2] = oa;        // overwrite own row (outT alias)
                xT[base1 + s2] = ob;
            } else {
                out[s2 * 12288 + b * 768 + d] = oa;
                out[s2 * 12288 + (b + 1) * 768 + d] = ob;
            }
        }
    }
}

// ---------------- P4: xT (BD,S) -> out (S,BD), 64x64 tiles --------------------
__global__ __launch_bounds__(256) void transpose_out(const float* __restrict__ xT,
                                                     float* __restrict__ out) {
    __shared__ float t[64][65];
    int bR = blockIdx.x % 192, bS = blockIdx.x / 192;
    int r0 = bR * 64, s0 = bS * 64;
    int c = threadIdx.x & 63, w = threadIdx.x >> 6;
#pragma unroll
    for (int k = 0; k < 16; ++k) {
        int row = w + 4 * k;
        t[row][c] = xT[(size_t)(r0 + row) * 1024 + s0 + c];
    }
    __syncthreads();
#pragma unroll
    for (int k = 0; k < 16; ++k) {
        int row = w + 4 * k;
        out[(size_t)(s0 + row) * 12288 + r0 + c] = t[c][row];
    }
}

extern "C" void kernel_launch(void* const* d_in, const int* in_sizes, int n_in,
                              void* d_out, int out_size, void* d_ws, size_t ws_size,
                              hipStream_t stream) {
    const float* x     = (const float*)d_in[0];
    const float* Aang  = (const float*)d_in[1];
    const float* Arad  = (const float*)d_in[2];
    const float* B1p   = (const float*)d_in[3];
    const float* B2p   = (const float*)d_in[4];
    const float* C1p   = (const float*)d_in[5];
    const float* C2p   = (const float*)d_in[6];
    const float* omega = (const float*)d_in[7];
    float* out = (float*)d_out;
    char* ws = (char*)d_ws;

    f2*    Gf = (f2*)ws;                            // 25,165,824 B
    float* xT = (float*)(ws + 25165824);            // 50,331,648 B (in+out alias)
    int useT = (ws_size >= (size_t)75497472) ? 1 : 0;

    int grid1 = useT ? 3840 : 768;   // 768 ssm blocks + 3072 transpose blocks
    ssm_tin<<<grid1, 512, 0, stream>>>(Aang, Arad, B1p, B2p, C1p, C2p, Gf, x, xT);
    conv_fft<<<6144, 512, 0, stream>>>(x, xT, Gf, omega, out, useT);
    if (useT) transpose_out<<<3072, 256, 0, stream>>>(xT, out);
}